// Round 4
// baseline (2215.310 us; speedup 1.0000x reference)
//
#include <hip/hip_runtime.h>

#define N_NODES 100000
#define N_EDGES 3200000
#define N_FEAT  128
#define DIM     48
#define N_CLASS 18
#define BN_EPS  1e-5f

#define PADK 132   // x-tile row stride (dwords); 132%32=4 -> 2-way bank alias (free)
#define PADD 52    // 48-wide tile row stride; 52%32=20 -> 2-way bank alias (free)

#define BSH    7                                   // bucket = dst >> 7 (128 nodes)
#define BROWS  128                                 // nodes per bucket
#define NBUCK  ((N_NODES + BROWS - 1) / BROWS)     // 782
#define EPB    4096                                // edges per binning block
#define NBLK_E ((N_EDGES + EPB - 1) / EPB)         // 782

// ---------------- bucket-granular edge preprocessing ----------------

__global__ __launch_bounds__(256) void k_bhist(const int* __restrict__ ei,
                                               int* __restrict__ bcnt) {
    __shared__ int h[NBUCK];
    const int t = threadIdx.x;
    for (int i = t; i < NBUCK; i += 256) h[i] = 0;
    __syncthreads();
    int bs = blockIdx.x * EPB;
    int ce = min(EPB, N_EDGES - bs);
    for (int i = t; i < ce; i += 256) {
        int d = ei[N_EDGES + bs + i];
        atomicAdd(&h[d >> BSH], 1);
    }
    __syncthreads();
    for (int i = t; i < NBUCK; i += 256)
        if (h[i]) atomicAdd(&bcnt[i], h[i]);
}

__global__ __launch_bounds__(1024) void k_bscan(const int* __restrict__ bcnt,
                                                int* __restrict__ bptr,
                                                int* __restrict__ bcursor) {
    __shared__ int s[1024];
    const int t = threadIdx.x;
    int v = (t < NBUCK) ? bcnt[t] : 0;
    s[t] = v;
    __syncthreads();
    for (int off = 1; off < 1024; off <<= 1) {
        int u = (t >= off) ? s[t - off] : 0;
        __syncthreads();
        s[t] += u;
        __syncthreads();
    }
    if (t < NBUCK) {
        int excl = s[t] - v;
        bptr[t] = excl;
        bcursor[t] = excl;
        if (t == NBUCK - 1) bptr[NBUCK] = s[t];
    }
}

// LDS-staged binning: pairs get written in bucket-contiguous runs (coalesced-ish),
// one global reserve atomic per (block,bucket) instead of one per edge.
__global__ __launch_bounds__(256) void k_bin(const int* __restrict__ ei,
                                             int* __restrict__ bcursor,
                                             int2* __restrict__ pairs) {
    __shared__ int h[NBUCK];       // counts, then adj (gbase - lscan)
    __shared__ int pos[NBUCK];     // exclusive scan, then bumped during scatter
    __shared__ int partial[256];
    __shared__ int2 stg[EPB];
    const int t = threadIdx.x;
    const int bs = blockIdx.x * EPB;
    const int ce = min(EPB, N_EDGES - bs);

    int sv[16], dv[16];
    #pragma unroll
    for (int i = 0; i < 16; i++) {
        int e = t + i * 256;
        if (e < ce) { sv[i] = ei[bs + e]; dv[i] = ei[N_EDGES + bs + e]; }
        else { sv[i] = 0; dv[i] = -1; }
    }
    for (int i = t; i < NBUCK; i += 256) h[i] = 0;
    __syncthreads();
    #pragma unroll
    for (int i = 0; i < 16; i++)
        if (dv[i] >= 0) atomicAdd(&h[dv[i] >> BSH], 1);
    __syncthreads();

    // exclusive scan of h over NBUCK buckets (4 per thread + 256-wide H-S scan)
    const int c0 = t * 4;
    int l0 = 0, l1 = 0, l2 = 0, l3 = 0, sum = 0;
    if (c0 < NBUCK) {
        l0 = h[c0]; sum = l0;
        if (c0 + 1 < NBUCK) { l1 = h[c0 + 1]; sum += l1; }
        if (c0 + 2 < NBUCK) { l2 = h[c0 + 2]; sum += l2; }
        if (c0 + 3 < NBUCK) { l3 = h[c0 + 3]; sum += l3; }
    }
    partial[t] = sum;
    __syncthreads();
    for (int off = 1; off < 256; off <<= 1) {
        int u = (t >= off) ? partial[t - off] : 0;
        __syncthreads();
        partial[t] += u;
        __syncthreads();
    }
    int run = partial[t] - sum;
    if (c0 < NBUCK) {
        pos[c0] = run; run += l0;
        if (c0 + 1 < NBUCK) { pos[c0 + 1] = run; run += l1; }
        if (c0 + 2 < NBUCK) { pos[c0 + 2] = run; run += l2; }
        if (c0 + 3 < NBUCK) { pos[c0 + 3] = run; run += l3; }
    }
    __syncthreads();

    // reserve global space; h[b] becomes adj = gbase - local_scan
    for (int b = t; b < NBUCK; b += 256) {
        int cnt = h[b];
        if (cnt > 0) {
            int g = atomicAdd(&bcursor[b], cnt);
            h[b] = g - pos[b];
        }
    }
    __syncthreads();

    // scatter into LDS staging (compact [0, ce))
    #pragma unroll
    for (int i = 0; i < 16; i++) {
        if (dv[i] >= 0) {
            int b = dv[i] >> BSH;
            int p = atomicAdd(&pos[b], 1);
            stg[p] = make_int2(sv[i], dv[i]);
        }
    }
    __syncthreads();

    // copy out: consecutive staged slots in a bucket run -> consecutive global
    for (int j = t; j < ce; j += 256) {
        int2 pr = stg[j];
        pairs[j + h[pr.y >> BSH]] = pr;
    }
}

// ---------------- conv1 front: t1 = x@W1, t2 = relu(x)@W1 ----------------

__global__ __launch_bounds__(256) void k_g1(const float* __restrict__ x,
                                            const float* __restrict__ W1,
                                            float* __restrict__ t1,
                                            float* __restrict__ t2) {
    __shared__ float sX[64 * PADK];
    __shared__ float sW[DIM * PADK];   // W1^T: [col][k]
    const int t = threadIdx.x;
    const int base = blockIdx.x * 64;

    for (int idx = t; idx < N_FEAT * DIM; idx += 256) {
        int k = idx / DIM, c = idx - k * DIM;
        sW[c * PADK + k] = W1[idx];
    }
    for (int idx = t; idx < 64 * 32; idx += 256) {
        int row = idx >> 5, kq = idx & 31;
        float4 v = make_float4(0.f, 0.f, 0.f, 0.f);
        if (base + row < N_NODES) v = ((const float4*)x)[(base + row) * 32 + kq];
        *(float4*)&sX[row * PADK + kq * 4] = v;
    }
    __syncthreads();

    const int cg = t & 7;
    const int rg = t >> 3;
    const int r0 = rg * 2;
    const int c0 = cg * 6;

    float a1[2][6], a2[2][6];
    #pragma unroll
    for (int r = 0; r < 2; r++)
        #pragma unroll
        for (int c = 0; c < 6; c++) { a1[r][c] = 0.f; a2[r][c] = 0.f; }

    #pragma unroll 2
    for (int kq = 0; kq < 32; kq++) {
        float4 x0 = *(const float4*)&sX[(r0 + 0) * PADK + kq * 4];
        float4 x1 = *(const float4*)&sX[(r0 + 1) * PADK + kq * 4];
        float4 p0 = make_float4(fmaxf(x0.x, 0.f), fmaxf(x0.y, 0.f), fmaxf(x0.z, 0.f), fmaxf(x0.w, 0.f));
        float4 p1 = make_float4(fmaxf(x1.x, 0.f), fmaxf(x1.y, 0.f), fmaxf(x1.z, 0.f), fmaxf(x1.w, 0.f));
        #pragma unroll
        for (int c = 0; c < 6; c++) {
            float4 w = *(const float4*)&sW[(c0 + c) * PADK + kq * 4];
            a1[0][c] += x0.x * w.x + x0.y * w.y + x0.z * w.z + x0.w * w.w;
            a1[1][c] += x1.x * w.x + x1.y * w.y + x1.z * w.z + x1.w * w.w;
            a2[0][c] += p0.x * w.x + p0.y * w.y + p0.z * w.z + p0.w * w.w;
            a2[1][c] += p1.x * w.x + p1.y * w.y + p1.z * w.z + p1.w * w.w;
        }
    }

    #pragma unroll
    for (int r = 0; r < 2; r++) {
        int gr = base + r0 + r;
        if (gr < N_NODES) {
            #pragma unroll
            for (int c = 0; c < 3; c++) {
                *(float2*)&t1[gr * DIM + c0 + 2 * c] = make_float2(a1[r][2 * c], a1[r][2 * c + 1]);
                *(float2*)&t2[gr * DIM + c0 + 2 * c] = make_float2(a2[r][2 * c], a2[r][2 * c + 1]);
            }
        }
    }
}

// ---------------- fused bucket aggregation ----------------
// One block per 128-node bucket. LDS f32 accumulator + ds_add_f32 atomics.
// out aliases tlin: final loop reads tlin[n,f] then writes out[n,f] (same thread);
// gathers touch only tmsg; rows are bucket-exclusive. Safe.

__global__ __launch_bounds__(256) void k_aggr2(const float* tlin,
                                               const float* __restrict__ tmsg,
                                               const int* __restrict__ bptr,
                                               const int2* __restrict__ pairs,
                                               const float* __restrict__ bias,
                                               float* out) {
    __shared__ float acc[BROWS * DIM];   // 24.6 KB
    const int t = threadIdx.x;
    const int b = blockIdx.x;
    const int nbase = b << BSH;
    for (int i = t; i < BROWS * DIM; i += 256) acc[i] = 0.f;
    __syncthreads();

    const int start = bptr[b], end = bptr[b + 1];
    const int cnt = end - start;
    const int wid = t >> 6, lane = t & 63;
    const bool act = lane < DIM;
    int per = (cnt + 3) >> 2;
    int wbeg = start + wid * per;
    int wend = wbeg + per; if (wend > end) wend = end;

    int e = wbeg;
    for (; e + 4 <= wend; e += 4) {
        int2 p0 = pairs[e], p1 = pairs[e + 1], p2 = pairs[e + 2], p3 = pairs[e + 3];
        if (act) {
            float v0 = tmsg[p0.x * DIM + lane];
            float v1 = tmsg[p1.x * DIM + lane];
            float v2 = tmsg[p2.x * DIM + lane];
            float v3 = tmsg[p3.x * DIM + lane];
            atomicAdd(&acc[(p0.y - nbase) * DIM + lane], v0);
            atomicAdd(&acc[(p1.y - nbase) * DIM + lane], v1);
            atomicAdd(&acc[(p2.y - nbase) * DIM + lane], v2);
            atomicAdd(&acc[(p3.y - nbase) * DIM + lane], v3);
        }
    }
    for (; e < wend; e++) {
        int2 p = pairs[e];
        if (act) {
            float v = tmsg[p.x * DIM + lane];
            atomicAdd(&acc[(p.y - nbase) * DIM + lane], v);
        }
    }
    __syncthreads();

    for (int i = t; i < BROWS * DIM; i += 256) {
        int row = i / DIM;
        int n = nbase + row;
        if (n < N_NODES) {
            int f = i - row * DIM;
            float base = tlin[n * DIM + f];
            out[n * DIM + f] = fmaxf(base + acc[i] + bias[f], 0.f);
        }
    }
}

// ---------------- chain1: v=u@c1W2+b2; g1=bn1(relu(v)); t3=g1@c2W1; t4=relu(g1)@c2W1 ----------------
// t3 aliases u: u fully staged to LDS before first sync; writes after; row-exclusive.

__global__ __launch_bounds__(256) void k_chain1(const float* u,
                                                const float* __restrict__ W2,
                                                const float* __restrict__ b2,
                                                const float* __restrict__ bng,
                                                const float* __restrict__ bnb,
                                                const float* __restrict__ bnm,
                                                const float* __restrict__ bnv,
                                                const float* __restrict__ W1n,
                                                float* t3,
                                                float* __restrict__ t4) {
    __shared__ float sU[64 * PADD];
    __shared__ float sG[64 * PADD];
    __shared__ float sW2[DIM * PADD];
    __shared__ float sW1[DIM * PADD];
    const int t = threadIdx.x;
    const int base = blockIdx.x * 64;

    for (int idx = t; idx < DIM * DIM; idx += 256) {
        int k = idx / DIM, c = idx - k * DIM;
        sW2[c * PADD + k] = W2[idx];
        sW1[c * PADD + k] = W1n[idx];
    }
    for (int idx = t; idx < 64 * 12; idx += 256) {
        int row = idx / 12, kq = idx - row * 12;
        float4 v = make_float4(0.f, 0.f, 0.f, 0.f);
        if (base + row < N_NODES) v = ((const float4*)u)[(base + row) * 12 + kq];
        *(float4*)&sU[row * PADD + kq * 4] = v;
    }
    __syncthreads();

    const int cg = t & 7, rg = t >> 3;
    const int r0 = rg * 2, c0 = cg * 6;

    {
        float g[2][6];
        #pragma unroll
        for (int r = 0; r < 2; r++)
            #pragma unroll
            for (int c = 0; c < 6; c++) g[r][c] = 0.f;

        #pragma unroll 2
        for (int kq = 0; kq < 12; kq++) {
            float4 x0 = *(const float4*)&sU[(r0 + 0) * PADD + kq * 4];
            float4 x1 = *(const float4*)&sU[(r0 + 1) * PADD + kq * 4];
            #pragma unroll
            for (int c = 0; c < 6; c++) {
                float4 w = *(const float4*)&sW2[(c0 + c) * PADD + kq * 4];
                g[0][c] += x0.x * w.x + x0.y * w.y + x0.z * w.z + x0.w * w.w;
                g[1][c] += x1.x * w.x + x1.y * w.y + x1.z * w.z + x1.w * w.w;
            }
        }
        #pragma unroll
        for (int c = 0; c < 6; c++) {
            float bb = b2[c0 + c];
            float sc = bng[c0 + c] * rsqrtf(bnv[c0 + c] + BN_EPS);
            float sh = bnb[c0 + c] - bnm[c0 + c] * sc;
            #pragma unroll
            for (int r = 0; r < 2; r++) {
                float rl = fmaxf(g[r][c] + bb, 0.f);
                sG[(r0 + r) * PADD + c0 + c] = rl * sc + sh;
            }
        }
    }
    __syncthreads();

    {
        float a3[2][6], a4[2][6];
        #pragma unroll
        for (int r = 0; r < 2; r++)
            #pragma unroll
            for (int c = 0; c < 6; c++) { a3[r][c] = 0.f; a4[r][c] = 0.f; }

        #pragma unroll 2
        for (int kq = 0; kq < 12; kq++) {
            float4 x0 = *(const float4*)&sG[(r0 + 0) * PADD + kq * 4];
            float4 x1 = *(const float4*)&sG[(r0 + 1) * PADD + kq * 4];
            float4 p0 = make_float4(fmaxf(x0.x, 0.f), fmaxf(x0.y, 0.f), fmaxf(x0.z, 0.f), fmaxf(x0.w, 0.f));
            float4 p1 = make_float4(fmaxf(x1.x, 0.f), fmaxf(x1.y, 0.f), fmaxf(x1.z, 0.f), fmaxf(x1.w, 0.f));
            #pragma unroll
            for (int c = 0; c < 6; c++) {
                float4 w = *(const float4*)&sW1[(c0 + c) * PADD + kq * 4];
                a3[0][c] += x0.x * w.x + x0.y * w.y + x0.z * w.z + x0.w * w.w;
                a3[1][c] += x1.x * w.x + x1.y * w.y + x1.z * w.z + x1.w * w.w;
                a4[0][c] += p0.x * w.x + p0.y * w.y + p0.z * w.z + p0.w * w.w;
                a4[1][c] += p1.x * w.x + p1.y * w.y + p1.z * w.z + p1.w * w.w;
            }
        }
        #pragma unroll
        for (int r = 0; r < 2; r++) {
            int gr = base + r0 + r;
            if (gr < N_NODES) {
                #pragma unroll
                for (int c = 0; c < 3; c++) {
                    *(float2*)&t3[gr * DIM + c0 + 2 * c] = make_float2(a3[r][2 * c], a3[r][2 * c + 1]);
                    *(float2*)&t4[gr * DIM + c0 + 2 * c] = make_float2(a4[r][2 * c], a4[r][2 * c + 1]);
                }
            }
        }
    }
}

// ---------------- chain2: v2=u2@c2W2+b2; g2=bn2(relu); z=relu(g2@fc1+b); out=z@fc2+b ----------------

__global__ __launch_bounds__(256) void k_chain2(const float* __restrict__ u2,
                                                const float* __restrict__ W2,
                                                const float* __restrict__ b2,
                                                const float* __restrict__ bng,
                                                const float* __restrict__ bnb,
                                                const float* __restrict__ bnm,
                                                const float* __restrict__ bnv,
                                                const float* __restrict__ fc1W,
                                                const float* __restrict__ fc1b,
                                                const float* __restrict__ fc2W,
                                                const float* __restrict__ fc2b,
                                                float* __restrict__ out) {
    __shared__ float sA[64 * PADD];
    __shared__ float sB[64 * PADD];
    __shared__ float sWa[DIM * PADD];
    __shared__ float sWb[DIM * PADD];
    __shared__ float sWc[N_CLASS * PADD];
    const int t = threadIdx.x;
    const int base = blockIdx.x * 64;

    for (int idx = t; idx < DIM * DIM; idx += 256) {
        int k = idx / DIM, c = idx - k * DIM;
        sWa[c * PADD + k] = W2[idx];
        sWb[c * PADD + k] = fc1W[idx];
    }
    for (int idx = t; idx < DIM * N_CLASS; idx += 256) {
        int k = idx / N_CLASS, c = idx - k * N_CLASS;
        sWc[c * PADD + k] = fc2W[idx];
    }
    for (int idx = t; idx < 64 * 12; idx += 256) {
        int row = idx / 12, kq = idx - row * 12;
        float4 v = make_float4(0.f, 0.f, 0.f, 0.f);
        if (base + row < N_NODES) v = ((const float4*)u2)[(base + row) * 12 + kq];
        *(float4*)&sA[row * PADD + kq * 4] = v;
    }
    __syncthreads();

    const int cg = t & 7, rg = t >> 3;
    const int r0 = rg * 2, c0 = cg * 6;

    {
        float g[2][6];
        #pragma unroll
        for (int r = 0; r < 2; r++)
            #pragma unroll
            for (int c = 0; c < 6; c++) g[r][c] = 0.f;
        #pragma unroll 2
        for (int kq = 0; kq < 12; kq++) {
            float4 x0 = *(const float4*)&sA[(r0 + 0) * PADD + kq * 4];
            float4 x1 = *(const float4*)&sA[(r0 + 1) * PADD + kq * 4];
            #pragma unroll
            for (int c = 0; c < 6; c++) {
                float4 w = *(const float4*)&sWa[(c0 + c) * PADD + kq * 4];
                g[0][c] += x0.x * w.x + x0.y * w.y + x0.z * w.z + x0.w * w.w;
                g[1][c] += x1.x * w.x + x1.y * w.y + x1.z * w.z + x1.w * w.w;
            }
        }
        #pragma unroll
        for (int c = 0; c < 6; c++) {
            float bb = b2[c0 + c];
            float sc = bng[c0 + c] * rsqrtf(bnv[c0 + c] + BN_EPS);
            float sh = bnb[c0 + c] - bnm[c0 + c] * sc;
            #pragma unroll
            for (int r = 0; r < 2; r++) {
                float rl = fmaxf(g[r][c] + bb, 0.f);
                sB[(r0 + r) * PADD + c0 + c] = rl * sc + sh;
            }
        }
    }
    __syncthreads();

    {
        float z[2][6];
        #pragma unroll
        for (int r = 0; r < 2; r++)
            #pragma unroll
            for (int c = 0; c < 6; c++) z[r][c] = 0.f;
        #pragma unroll 2
        for (int kq = 0; kq < 12; kq++) {
            float4 x0 = *(const float4*)&sB[(r0 + 0) * PADD + kq * 4];
            float4 x1 = *(const float4*)&sB[(r0 + 1) * PADD + kq * 4];
            #pragma unroll
            for (int c = 0; c < 6; c++) {
                float4 w = *(const float4*)&sWb[(c0 + c) * PADD + kq * 4];
                z[0][c] += x0.x * w.x + x0.y * w.y + x0.z * w.z + x0.w * w.w;
                z[1][c] += x1.x * w.x + x1.y * w.y + x1.z * w.z + x1.w * w.w;
            }
        }
        __syncthreads();
        #pragma unroll
        for (int c = 0; c < 6; c++) {
            float bb = fc1b[c0 + c];
            #pragma unroll
            for (int r = 0; r < 2; r++)
                sA[(r0 + r) * PADD + c0 + c] = fmaxf(z[r][c] + bb, 0.f);
        }
    }
    __syncthreads();

    if (cg < 6) {
        const int cc0 = cg * 3;
        float o[2][3];
        #pragma unroll
        for (int r = 0; r < 2; r++)
            #pragma unroll
            for (int c = 0; c < 3; c++) o[r][c] = 0.f;
        #pragma unroll 2
        for (int kq = 0; kq < 12; kq++) {
            float4 x0 = *(const float4*)&sA[(r0 + 0) * PADD + kq * 4];
            float4 x1 = *(const float4*)&sA[(r0 + 1) * PADD + kq * 4];
            #pragma unroll
            for (int c = 0; c < 3; c++) {
                float4 w = *(const float4*)&sWc[(cc0 + c) * PADD + kq * 4];
                o[0][c] += x0.x * w.x + x0.y * w.y + x0.z * w.z + x0.w * w.w;
                o[1][c] += x1.x * w.x + x1.y * w.y + x1.z * w.z + x1.w * w.w;
            }
        }
        #pragma unroll
        for (int r = 0; r < 2; r++) {
            int gr = base + r0 + r;
            if (gr < N_NODES) {
                #pragma unroll
                for (int c = 0; c < 3; c++)
                    out[gr * N_CLASS + cc0 + c] = o[r][c] + fc2b[cc0 + c];
            }
        }
    }
}

// ---------------- launch ----------------

extern "C" void kernel_launch(void* const* d_in, const int* in_sizes, int n_in,
                              void* d_out, int out_size, void* d_ws, size_t ws_size,
                              hipStream_t stream) {
    const float* x     = (const float*)d_in[0];
    const int*   ei    = (const int*)d_in[1];
    const float* c1_W1 = (const float*)d_in[2];
    const float* c1_b1 = (const float*)d_in[3];
    const float* c1_W2 = (const float*)d_in[4];
    const float* c1_b2 = (const float*)d_in[5];
    const float* c2_W1 = (const float*)d_in[6];
    const float* c2_b1 = (const float*)d_in[7];
    const float* c2_W2 = (const float*)d_in[8];
    const float* c2_b2 = (const float*)d_in[9];
    const float* bn1_g = (const float*)d_in[10];
    const float* bn1_b = (const float*)d_in[11];
    const float* bn1_m = (const float*)d_in[12];
    const float* bn1_v = (const float*)d_in[13];
    const float* bn2_g = (const float*)d_in[14];
    const float* bn2_b = (const float*)d_in[15];
    const float* bn2_m = (const float*)d_in[16];
    const float* bn2_v = (const float*)d_in[17];
    const float* fc1_W = (const float*)d_in[18];
    const float* fc1_b = (const float*)d_in[19];
    const float* fc2_W = (const float*)d_in[20];
    const float* fc2_b = (const float*)d_in[21];
    float* out = (float*)d_out;

    char* ws = (char*)d_ws;
    size_t o = 0;
    auto take = [&](size_t bytes) {
        void* p = ws + o;
        o = (o + bytes + 255) & ~(size_t)255;
        return p;
    };
    int2* pairs   = (int2*)take((size_t)N_EDGES * 8);          // 25.6 MB
    int*  bcnt    = (int*)take((size_t)NBUCK * 4);
    int*  bptr    = (int*)take((size_t)(NBUCK + 1) * 4);
    int*  bcursor = (int*)take((size_t)NBUCK * 4);
    float* t1     = (float*)take((size_t)N_NODES * DIM * 4);   // aliased: t1/u/t3/u2
    float* t2     = (float*)take((size_t)N_NODES * DIM * 4);   // t2/t4
    (void)ws_size; (void)in_sizes; (void)n_in; (void)out_size;

    const int NB64 = (N_NODES + 63) / 64;   // 1563

    hipMemsetAsync(bcnt, 0, (size_t)NBUCK * 4, stream);
    k_bhist<<<NBLK_E, 256, 0, stream>>>(ei, bcnt);
    k_bscan<<<1, 1024, 0, stream>>>(bcnt, bptr, bcursor);
    k_bin<<<NBLK_E, 256, 0, stream>>>(ei, bcursor, pairs);

    k_g1<<<NB64, 256, 0, stream>>>(x, c1_W1, t1, t2);
    k_aggr2<<<NBUCK, 256, 0, stream>>>(t1, t2, bptr, pairs, c1_b1, t1);
    k_chain1<<<NB64, 256, 0, stream>>>(t1, c1_W2, c1_b2, bn1_g, bn1_b, bn1_m, bn1_v,
                                       c2_W1, t1, t2);
    k_aggr2<<<NBUCK, 256, 0, stream>>>(t1, t2, bptr, pairs, c2_b1, t1);
    k_chain2<<<NB64, 256, 0, stream>>>(t1, c2_W2, c2_b2, bn2_g, bn2_b, bn2_m, bn2_v,
                                       fc1_W, fc1_b, fc2_W, fc2_b, out);
}

// Round 5
// 434.646 us; speedup vs baseline: 5.0968x; 5.0968x over previous
//
#include <hip/hip_runtime.h>

#define N_NODES 100000
#define N_EDGES 3200000
#define N_FEAT  128
#define DIM     48
#define N_CLASS 18
#define BN_EPS  1e-5f

#define PADK 132   // x-tile row stride (dwords); 132%32=4 -> 2-way bank alias (free)
#define PADD 52    // 48-wide tile row stride; 52%32=20 -> 2-way bank alias (free)

#define BSH    7                                   // bucket = dst >> 7 (128 nodes)
#define BROWS  128                                 // nodes per bucket
#define NBUCK  ((N_NODES + BROWS - 1) / BROWS)     // 782
#define EPB    4096                                // edges per binning block
#define NBLK_E ((N_EDGES + EPB - 1) / EPB)         // 782

// ---------------- bucket-granular edge preprocessing ----------------

__global__ __launch_bounds__(256) void k_bhist(const int* __restrict__ ei,
                                               int* __restrict__ bcnt) {
    __shared__ int h[NBUCK];
    const int t = threadIdx.x;
    for (int i = t; i < NBUCK; i += 256) h[i] = 0;
    __syncthreads();
    int bs = blockIdx.x * EPB;
    int ce = min(EPB, N_EDGES - bs);
    for (int i = t; i < ce; i += 256) {
        int d = ei[N_EDGES + bs + i];
        atomicAdd(&h[d >> BSH], 1);
    }
    __syncthreads();
    for (int i = t; i < NBUCK; i += 256)
        if (h[i]) atomicAdd(&bcnt[i], h[i]);
}

__global__ __launch_bounds__(1024) void k_bscan(const int* __restrict__ bcnt,
                                                int* __restrict__ bptr,
                                                int* __restrict__ bcursor) {
    __shared__ int s[1024];
    const int t = threadIdx.x;
    int v = (t < NBUCK) ? bcnt[t] : 0;
    s[t] = v;
    __syncthreads();
    for (int off = 1; off < 1024; off <<= 1) {
        int u = (t >= off) ? s[t - off] : 0;
        __syncthreads();
        s[t] += u;
        __syncthreads();
    }
    if (t < NBUCK) {
        int excl = s[t] - v;
        bptr[t] = excl;
        bcursor[t] = excl;
        if (t == NBUCK - 1) bptr[NBUCK] = s[t];
    }
}

// LDS-staged binning: pairs get written in bucket-contiguous runs (coalesced-ish),
// one global reserve atomic per (block,bucket) instead of one per edge.
__global__ __launch_bounds__(256) void k_bin(const int* __restrict__ ei,
                                             int* __restrict__ bcursor,
                                             int2* __restrict__ pairs) {
    __shared__ int h[NBUCK];       // counts, then adj (gbase - lscan)
    __shared__ int pos[NBUCK];     // exclusive scan, then bumped during scatter
    __shared__ int partial[256];
    __shared__ int2 stg[EPB];
    const int t = threadIdx.x;
    const int bs = blockIdx.x * EPB;
    const int ce = min(EPB, N_EDGES - bs);

    int sv[16], dv[16];
    #pragma unroll
    for (int i = 0; i < 16; i++) {
        int e = t + i * 256;
        if (e < ce) { sv[i] = ei[bs + e]; dv[i] = ei[N_EDGES + bs + e]; }
        else { sv[i] = 0; dv[i] = -1; }
    }
    for (int i = t; i < NBUCK; i += 256) h[i] = 0;
    __syncthreads();
    #pragma unroll
    for (int i = 0; i < 16; i++)
        if (dv[i] >= 0) atomicAdd(&h[dv[i] >> BSH], 1);
    __syncthreads();

    const int c0 = t * 4;
    int l0 = 0, l1 = 0, l2 = 0, l3 = 0, sum = 0;
    if (c0 < NBUCK) {
        l0 = h[c0]; sum = l0;
        if (c0 + 1 < NBUCK) { l1 = h[c0 + 1]; sum += l1; }
        if (c0 + 2 < NBUCK) { l2 = h[c0 + 2]; sum += l2; }
        if (c0 + 3 < NBUCK) { l3 = h[c0 + 3]; sum += l3; }
    }
    partial[t] = sum;
    __syncthreads();
    for (int off = 1; off < 256; off <<= 1) {
        int u = (t >= off) ? partial[t - off] : 0;
        __syncthreads();
        partial[t] += u;
        __syncthreads();
    }
    int run = partial[t] - sum;
    if (c0 < NBUCK) {
        pos[c0] = run; run += l0;
        if (c0 + 1 < NBUCK) { pos[c0 + 1] = run; run += l1; }
        if (c0 + 2 < NBUCK) { pos[c0 + 2] = run; run += l2; }
        if (c0 + 3 < NBUCK) { pos[c0 + 3] = run; run += l3; }
    }
    __syncthreads();

    for (int b = t; b < NBUCK; b += 256) {
        int cnt = h[b];
        if (cnt > 0) {
            int g = atomicAdd(&bcursor[b], cnt);
            h[b] = g - pos[b];
        }
    }
    __syncthreads();

    #pragma unroll
    for (int i = 0; i < 16; i++) {
        if (dv[i] >= 0) {
            int b = dv[i] >> BSH;
            int p = atomicAdd(&pos[b], 1);
            stg[p] = make_int2(sv[i], dv[i]);
        }
    }
    __syncthreads();

    for (int j = t; j < ce; j += 256) {
        int2 pr = stg[j];
        pairs[j + h[pr.y >> BSH]] = pr;
    }
}

// ---------------- per-bucket exact counting sort -> CSR (row_ptr, sorted_src) ----------------
// Two streaming passes over the bucket's pairs; 1 KB LDS; writes land in the
// bucket's contiguous ~16 KB window of sorted_src (L2-absorbed).

__global__ __launch_bounds__(256) void k_sort(const int2* __restrict__ pairs,
                                              const int* __restrict__ bptr,
                                              int* __restrict__ row_ptr,
                                              int* __restrict__ sorted_src) {
    __shared__ int hist[BROWS];
    __shared__ int pos[BROWS];
    const int t = threadIdx.x;
    const int b = blockIdx.x;
    const int nbase = b << BSH;
    const int start = bptr[b], end = bptr[b + 1];

    if (t < BROWS) hist[t] = 0;
    __syncthreads();
    for (int e = start + t; e < end; e += 256) {
        int d = pairs[e].y;
        atomicAdd(&hist[d - nbase], 1);
    }
    __syncthreads();
    if (t < BROWS) pos[t] = hist[t];
    __syncthreads();
    for (int off = 1; off < BROWS; off <<= 1) {
        int v = 0;
        if (t < BROWS && t >= off) v = pos[t - off];
        __syncthreads();
        if (t < BROWS) pos[t] += v;
        __syncthreads();
    }
    if (t < BROWS) {
        int rp = start + pos[t] - hist[t];   // exclusive + bucket base
        int n = nbase + t;
        if (n < N_NODES) row_ptr[n] = rp;
        pos[t] = rp;
    }
    if (b == 0 && t == 0) row_ptr[N_NODES] = N_EDGES;
    __syncthreads();
    for (int e = start + t; e < end; e += 256) {
        int2 p = pairs[e];
        int idx = atomicAdd(&pos[p.y - nbase], 1);
        sorted_src[idx] = p.x;
    }
}

// ---------------- conv1 front: t1 = x@W1, t2 = relu(x)@W1 ----------------

__global__ __launch_bounds__(256) void k_g1(const float* __restrict__ x,
                                            const float* __restrict__ W1,
                                            float* __restrict__ t1,
                                            float* __restrict__ t2) {
    __shared__ float sX[64 * PADK];
    __shared__ float sW[DIM * PADK];   // W1^T: [col][k]
    const int t = threadIdx.x;
    const int base = blockIdx.x * 64;

    for (int idx = t; idx < N_FEAT * DIM; idx += 256) {
        int k = idx / DIM, c = idx - k * DIM;
        sW[c * PADK + k] = W1[idx];
    }
    for (int idx = t; idx < 64 * 32; idx += 256) {
        int row = idx >> 5, kq = idx & 31;
        float4 v = make_float4(0.f, 0.f, 0.f, 0.f);
        if (base + row < N_NODES) v = ((const float4*)x)[(base + row) * 32 + kq];
        *(float4*)&sX[row * PADK + kq * 4] = v;
    }
    __syncthreads();

    const int cg = t & 7;
    const int rg = t >> 3;
    const int r0 = rg * 2;
    const int c0 = cg * 6;

    float a1[2][6], a2[2][6];
    #pragma unroll
    for (int r = 0; r < 2; r++)
        #pragma unroll
        for (int c = 0; c < 6; c++) { a1[r][c] = 0.f; a2[r][c] = 0.f; }

    #pragma unroll 2
    for (int kq = 0; kq < 32; kq++) {
        float4 x0 = *(const float4*)&sX[(r0 + 0) * PADK + kq * 4];
        float4 x1 = *(const float4*)&sX[(r0 + 1) * PADK + kq * 4];
        float4 p0 = make_float4(fmaxf(x0.x, 0.f), fmaxf(x0.y, 0.f), fmaxf(x0.z, 0.f), fmaxf(x0.w, 0.f));
        float4 p1 = make_float4(fmaxf(x1.x, 0.f), fmaxf(x1.y, 0.f), fmaxf(x1.z, 0.f), fmaxf(x1.w, 0.f));
        #pragma unroll
        for (int c = 0; c < 6; c++) {
            float4 w = *(const float4*)&sW[(c0 + c) * PADK + kq * 4];
            a1[0][c] += x0.x * w.x + x0.y * w.y + x0.z * w.z + x0.w * w.w;
            a1[1][c] += x1.x * w.x + x1.y * w.y + x1.z * w.z + x1.w * w.w;
            a2[0][c] += p0.x * w.x + p0.y * w.y + p0.z * w.z + p0.w * w.w;
            a2[1][c] += p1.x * w.x + p1.y * w.y + p1.z * w.z + p1.w * w.w;
        }
    }

    #pragma unroll
    for (int r = 0; r < 2; r++) {
        int gr = base + r0 + r;
        if (gr < N_NODES) {
            #pragma unroll
            for (int c = 0; c < 3; c++) {
                *(float2*)&t1[gr * DIM + c0 + 2 * c] = make_float2(a1[r][2 * c], a1[r][2 * c + 1]);
                *(float2*)&t2[gr * DIM + c0 + 2 * c] = make_float2(a2[r][2 * c], a2[r][2 * c + 1]);
            }
        }
    }
}

// ---------------- aggregation: out = relu(tlin + segsum(tmsg) + bias) ----------------
// One wave per node (4 nodes/block, 25000 blocks -> full occupancy, deep TLP).
// out aliases tlin: each thread reads tlin[n,lane] before writing; row-exclusive.

__global__ __launch_bounds__(256) void k_aggr(const float* tlin,
                                              const float* __restrict__ tmsg,
                                              const int* __restrict__ row_ptr,
                                              const int* __restrict__ ssrc,
                                              const float* __restrict__ bias,
                                              float* out) {
    int n = blockIdx.x * 4 + (threadIdx.x >> 6);
    int lane = threadIdx.x & 63;
    if (n >= N_NODES) return;
    int start = row_ptr[n], end = row_ptr[n + 1];
    bool act = lane < DIM;
    float acc = 0.f;
    int e = start;
    for (; e + 8 <= end; e += 8) {
        int s0 = ssrc[e], s1 = ssrc[e + 1], s2 = ssrc[e + 2], s3 = ssrc[e + 3];
        int s4 = ssrc[e + 4], s5 = ssrc[e + 5], s6 = ssrc[e + 6], s7 = ssrc[e + 7];
        if (act) {
            float v0 = tmsg[s0 * DIM + lane];
            float v1 = tmsg[s1 * DIM + lane];
            float v2 = tmsg[s2 * DIM + lane];
            float v3 = tmsg[s3 * DIM + lane];
            float v4 = tmsg[s4 * DIM + lane];
            float v5 = tmsg[s5 * DIM + lane];
            float v6 = tmsg[s6 * DIM + lane];
            float v7 = tmsg[s7 * DIM + lane];
            acc += ((v0 + v1) + (v2 + v3)) + ((v4 + v5) + (v6 + v7));
        }
    }
    for (; e < end; e++) {
        int s = ssrc[e];
        if (act) acc += tmsg[s * DIM + lane];
    }
    if (act) {
        float base = tlin[n * DIM + lane];
        out[n * DIM + lane] = fmaxf(base + acc + bias[lane], 0.f);
    }
}

// ---------------- chain1: v=u@c1W2+b2; g1=bn1(relu(v)); t3=g1@c2W1; t4=relu(g1)@c2W1 ----------------
// t3 aliases u: u fully staged to LDS before first sync; writes after; row-exclusive.

__global__ __launch_bounds__(256) void k_chain1(const float* u,
                                                const float* __restrict__ W2,
                                                const float* __restrict__ b2,
                                                const float* __restrict__ bng,
                                                const float* __restrict__ bnb,
                                                const float* __restrict__ bnm,
                                                const float* __restrict__ bnv,
                                                const float* __restrict__ W1n,
                                                float* t3,
                                                float* __restrict__ t4) {
    __shared__ float sU[64 * PADD];
    __shared__ float sG[64 * PADD];
    __shared__ float sW2[DIM * PADD];
    __shared__ float sW1[DIM * PADD];
    const int t = threadIdx.x;
    const int base = blockIdx.x * 64;

    for (int idx = t; idx < DIM * DIM; idx += 256) {
        int k = idx / DIM, c = idx - k * DIM;
        sW2[c * PADD + k] = W2[idx];
        sW1[c * PADD + k] = W1n[idx];
    }
    for (int idx = t; idx < 64 * 12; idx += 256) {
        int row = idx / 12, kq = idx - row * 12;
        float4 v = make_float4(0.f, 0.f, 0.f, 0.f);
        if (base + row < N_NODES) v = ((const float4*)u)[(base + row) * 12 + kq];
        *(float4*)&sU[row * PADD + kq * 4] = v;
    }
    __syncthreads();

    const int cg = t & 7, rg = t >> 3;
    const int r0 = rg * 2, c0 = cg * 6;

    {
        float g[2][6];
        #pragma unroll
        for (int r = 0; r < 2; r++)
            #pragma unroll
            for (int c = 0; c < 6; c++) g[r][c] = 0.f;

        #pragma unroll 2
        for (int kq = 0; kq < 12; kq++) {
            float4 x0 = *(const float4*)&sU[(r0 + 0) * PADD + kq * 4];
            float4 x1 = *(const float4*)&sU[(r0 + 1) * PADD + kq * 4];
            #pragma unroll
            for (int c = 0; c < 6; c++) {
                float4 w = *(const float4*)&sW2[(c0 + c) * PADD + kq * 4];
                g[0][c] += x0.x * w.x + x0.y * w.y + x0.z * w.z + x0.w * w.w;
                g[1][c] += x1.x * w.x + x1.y * w.y + x1.z * w.z + x1.w * w.w;
            }
        }
        #pragma unroll
        for (int c = 0; c < 6; c++) {
            float bb = b2[c0 + c];
            float sc = bng[c0 + c] * rsqrtf(bnv[c0 + c] + BN_EPS);
            float sh = bnb[c0 + c] - bnm[c0 + c] * sc;
            #pragma unroll
            for (int r = 0; r < 2; r++) {
                float rl = fmaxf(g[r][c] + bb, 0.f);
                sG[(r0 + r) * PADD + c0 + c] = rl * sc + sh;
            }
        }
    }
    __syncthreads();

    {
        float a3[2][6], a4[2][6];
        #pragma unroll
        for (int r = 0; r < 2; r++)
            #pragma unroll
            for (int c = 0; c < 6; c++) { a3[r][c] = 0.f; a4[r][c] = 0.f; }

        #pragma unroll 2
        for (int kq = 0; kq < 12; kq++) {
            float4 x0 = *(const float4*)&sG[(r0 + 0) * PADD + kq * 4];
            float4 x1 = *(const float4*)&sG[(r0 + 1) * PADD + kq * 4];
            float4 p0 = make_float4(fmaxf(x0.x, 0.f), fmaxf(x0.y, 0.f), fmaxf(x0.z, 0.f), fmaxf(x0.w, 0.f));
            float4 p1 = make_float4(fmaxf(x1.x, 0.f), fmaxf(x1.y, 0.f), fmaxf(x1.z, 0.f), fmaxf(x1.w, 0.f));
            #pragma unroll
            for (int c = 0; c < 6; c++) {
                float4 w = *(const float4*)&sW1[(c0 + c) * PADD + kq * 4];
                a3[0][c] += x0.x * w.x + x0.y * w.y + x0.z * w.z + x0.w * w.w;
                a3[1][c] += x1.x * w.x + x1.y * w.y + x1.z * w.z + x1.w * w.w;
                a4[0][c] += p0.x * w.x + p0.y * w.y + p0.z * w.z + p0.w * w.w;
                a4[1][c] += p1.x * w.x + p1.y * w.y + p1.z * w.z + p1.w * w.w;
            }
        }
        #pragma unroll
        for (int r = 0; r < 2; r++) {
            int gr = base + r0 + r;
            if (gr < N_NODES) {
                #pragma unroll
                for (int c = 0; c < 3; c++) {
                    *(float2*)&t3[gr * DIM + c0 + 2 * c] = make_float2(a3[r][2 * c], a3[r][2 * c + 1]);
                    *(float2*)&t4[gr * DIM + c0 + 2 * c] = make_float2(a4[r][2 * c], a4[r][2 * c + 1]);
                }
            }
        }
    }
}

// ---------------- chain2: v2=u2@c2W2+b2; g2=bn2(relu); z=relu(g2@fc1+b); out=z@fc2+b ----------------

__global__ __launch_bounds__(256) void k_chain2(const float* __restrict__ u2,
                                                const float* __restrict__ W2,
                                                const float* __restrict__ b2,
                                                const float* __restrict__ bng,
                                                const float* __restrict__ bnb,
                                                const float* __restrict__ bnm,
                                                const float* __restrict__ bnv,
                                                const float* __restrict__ fc1W,
                                                const float* __restrict__ fc1b,
                                                const float* __restrict__ fc2W,
                                                const float* __restrict__ fc2b,
                                                float* __restrict__ out) {
    __shared__ float sA[64 * PADD];
    __shared__ float sB[64 * PADD];
    __shared__ float sWa[DIM * PADD];
    __shared__ float sWb[DIM * PADD];
    __shared__ float sWc[N_CLASS * PADD];
    const int t = threadIdx.x;
    const int base = blockIdx.x * 64;

    for (int idx = t; idx < DIM * DIM; idx += 256) {
        int k = idx / DIM, c = idx - k * DIM;
        sWa[c * PADD + k] = W2[idx];
        sWb[c * PADD + k] = fc1W[idx];
    }
    for (int idx = t; idx < DIM * N_CLASS; idx += 256) {
        int k = idx / N_CLASS, c = idx - k * N_CLASS;
        sWc[c * PADD + k] = fc2W[idx];
    }
    for (int idx = t; idx < 64 * 12; idx += 256) {
        int row = idx / 12, kq = idx - row * 12;
        float4 v = make_float4(0.f, 0.f, 0.f, 0.f);
        if (base + row < N_NODES) v = ((const float4*)u2)[(base + row) * 12 + kq];
        *(float4*)&sA[row * PADD + kq * 4] = v;
    }
    __syncthreads();

    const int cg = t & 7, rg = t >> 3;
    const int r0 = rg * 2, c0 = cg * 6;

    {
        float g[2][6];
        #pragma unroll
        for (int r = 0; r < 2; r++)
            #pragma unroll
            for (int c = 0; c < 6; c++) g[r][c] = 0.f;
        #pragma unroll 2
        for (int kq = 0; kq < 12; kq++) {
            float4 x0 = *(const float4*)&sA[(r0 + 0) * PADD + kq * 4];
            float4 x1 = *(const float4*)&sA[(r0 + 1) * PADD + kq * 4];
            #pragma unroll
            for (int c = 0; c < 6; c++) {
                float4 w = *(const float4*)&sWa[(c0 + c) * PADD + kq * 4];
                g[0][c] += x0.x * w.x + x0.y * w.y + x0.z * w.z + x0.w * w.w;
                g[1][c] += x1.x * w.x + x1.y * w.y + x1.z * w.z + x1.w * w.w;
            }
        }
        #pragma unroll
        for (int c = 0; c < 6; c++) {
            float bb = b2[c0 + c];
            float sc = bng[c0 + c] * rsqrtf(bnv[c0 + c] + BN_EPS);
            float sh = bnb[c0 + c] - bnm[c0 + c] * sc;
            #pragma unroll
            for (int r = 0; r < 2; r++) {
                float rl = fmaxf(g[r][c] + bb, 0.f);
                sB[(r0 + r) * PADD + c0 + c] = rl * sc + sh;
            }
        }
    }
    __syncthreads();

    {
        float z[2][6];
        #pragma unroll
        for (int r = 0; r < 2; r++)
            #pragma unroll
            for (int c = 0; c < 6; c++) z[r][c] = 0.f;
        #pragma unroll 2
        for (int kq = 0; kq < 12; kq++) {
            float4 x0 = *(const float4*)&sB[(r0 + 0) * PADD + kq * 4];
            float4 x1 = *(const float4*)&sB[(r0 + 1) * PADD + kq * 4];
            #pragma unroll
            for (int c = 0; c < 6; c++) {
                float4 w = *(const float4*)&sWb[(c0 + c) * PADD + kq * 4];
                z[0][c] += x0.x * w.x + x0.y * w.y + x0.z * w.z + x0.w * w.w;
                z[1][c] += x1.x * w.x + x1.y * w.y + x1.z * w.z + x1.w * w.w;
            }
        }
        __syncthreads();
        #pragma unroll
        for (int c = 0; c < 6; c++) {
            float bb = fc1b[c0 + c];
            #pragma unroll
            for (int r = 0; r < 2; r++)
                sA[(r0 + r) * PADD + c0 + c] = fmaxf(z[r][c] + bb, 0.f);
        }
    }
    __syncthreads();

    if (cg < 6) {
        const int cc0 = cg * 3;
        float o[2][3];
        #pragma unroll
        for (int r = 0; r < 2; r++)
            #pragma unroll
            for (int c = 0; c < 3; c++) o[r][c] = 0.f;
        #pragma unroll 2
        for (int kq = 0; kq < 12; kq++) {
            float4 x0 = *(const float4*)&sA[(r0 + 0) * PADD + kq * 4];
            float4 x1 = *(const float4*)&sA[(r0 + 1) * PADD + kq * 4];
            #pragma unroll
            for (int c = 0; c < 3; c++) {
                float4 w = *(const float4*)&sWc[(cc0 + c) * PADD + kq * 4];
                o[0][c] += x0.x * w.x + x0.y * w.y + x0.z * w.z + x0.w * w.w;
                o[1][c] += x1.x * w.x + x1.y * w.y + x1.z * w.z + x1.w * w.w;
            }
        }
        #pragma unroll
        for (int r = 0; r < 2; r++) {
            int gr = base + r0 + r;
            if (gr < N_NODES) {
                #pragma unroll
                for (int c = 0; c < 3; c++)
                    out[gr * N_CLASS + cc0 + c] = o[r][c] + fc2b[cc0 + c];
            }
        }
    }
}

// ---------------- launch ----------------

extern "C" void kernel_launch(void* const* d_in, const int* in_sizes, int n_in,
                              void* d_out, int out_size, void* d_ws, size_t ws_size,
                              hipStream_t stream) {
    const float* x     = (const float*)d_in[0];
    const int*   ei    = (const int*)d_in[1];
    const float* c1_W1 = (const float*)d_in[2];
    const float* c1_b1 = (const float*)d_in[3];
    const float* c1_W2 = (const float*)d_in[4];
    const float* c1_b2 = (const float*)d_in[5];
    const float* c2_W1 = (const float*)d_in[6];
    const float* c2_b1 = (const float*)d_in[7];
    const float* c2_W2 = (const float*)d_in[8];
    const float* c2_b2 = (const float*)d_in[9];
    const float* bn1_g = (const float*)d_in[10];
    const float* bn1_b = (const float*)d_in[11];
    const float* bn1_m = (const float*)d_in[12];
    const float* bn1_v = (const float*)d_in[13];
    const float* bn2_g = (const float*)d_in[14];
    const float* bn2_b = (const float*)d_in[15];
    const float* bn2_m = (const float*)d_in[16];
    const float* bn2_v = (const float*)d_in[17];
    const float* fc1_W = (const float*)d_in[18];
    const float* fc1_b = (const float*)d_in[19];
    const float* fc2_W = (const float*)d_in[20];
    const float* fc2_b = (const float*)d_in[21];
    float* out = (float*)d_out;

    char* ws = (char*)d_ws;
    size_t o = 0;
    auto take = [&](size_t bytes) {
        void* p = ws + o;
        o = (o + bytes + 255) & ~(size_t)255;
        return p;
    };
    int2* pairs      = (int2*)take((size_t)N_EDGES * 8);          // 25.6 MB
    int*  sorted_src = (int*)take((size_t)N_EDGES * 4);           // 12.8 MB
    int*  row_ptr    = (int*)take((size_t)(N_NODES + 1) * 4);
    int*  bcnt       = (int*)take((size_t)NBUCK * 4);
    int*  bptr       = (int*)take((size_t)(NBUCK + 1) * 4);
    int*  bcursor    = (int*)take((size_t)NBUCK * 4);
    float* t1        = (float*)take((size_t)N_NODES * DIM * 4);   // aliased: t1/u/t3/u2
    float* t2        = (float*)take((size_t)N_NODES * DIM * 4);   // t2/t4
    (void)ws_size; (void)in_sizes; (void)n_in; (void)out_size;

    const int NB64 = (N_NODES + 63) / 64;   // 1563
    const int NB4  = (N_NODES + 3) / 4;     // 25000

    hipMemsetAsync(bcnt, 0, (size_t)NBUCK * 4, stream);
    k_bhist<<<NBLK_E, 256, 0, stream>>>(ei, bcnt);
    k_bscan<<<1, 1024, 0, stream>>>(bcnt, bptr, bcursor);
    k_bin<<<NBLK_E, 256, 0, stream>>>(ei, bcursor, pairs);
    k_sort<<<NBUCK, 256, 0, stream>>>(pairs, bptr, row_ptr, sorted_src);

    k_g1<<<NB64, 256, 0, stream>>>(x, c1_W1, t1, t2);
    k_aggr<<<NB4, 256, 0, stream>>>(t1, t2, row_ptr, sorted_src, c1_b1, t1);
    k_chain1<<<NB64, 256, 0, stream>>>(t1, c1_W2, c1_b2, bn1_g, bn1_b, bn1_m, bn1_v,
                                       c2_W1, t1, t2);
    k_aggr<<<NB4, 256, 0, stream>>>(t1, t2, row_ptr, sorted_src, c2_b1, t1);
    k_chain2<<<NB64, 256, 0, stream>>>(t1, c2_W2, c2_b2, bn2_g, bn2_b, bn2_m, bn2_v,
                                       fc1_W, fc1_b, fc2_W, fc2_b, out);
}

// Round 6
// 408.828 us; speedup vs baseline: 5.4187x; 1.0632x over previous
//
#include <hip/hip_runtime.h>
#include <hip/hip_fp16.h>

#define N_NODES 100000
#define N_EDGES 3200000
#define N_FEAT  128
#define DIM     48
#define N_CLASS 18
#define BN_EPS  1e-5f

#define PADK 132   // x-tile row stride (dwords); 132%32=4 -> 2-way bank alias (free)
#define PADD 52    // 48-wide tile row stride; 52%32=20 -> 2-way bank alias (free)

#define BSH    7                                   // bucket = dst >> 7 (128 nodes)
#define BROWS  128                                 // nodes per bucket
#define NBUCK  ((N_NODES + BROWS - 1) / BROWS)     // 782
#define EPB    4096                                // edges per binning block
#define NBLK_E ((N_EDGES + EPB - 1) / EPB)         // 782

// packed edge: (src << 7) | (dst & 127).  src < 2^17, fits 24 bits.

// ---------------- bucket-granular edge preprocessing ----------------

__global__ __launch_bounds__(256) void k_bhist(const int* __restrict__ ei,
                                               int* __restrict__ bcnt) {
    __shared__ int h[NBUCK];
    const int t = threadIdx.x;
    for (int i = t; i < NBUCK; i += 256) h[i] = 0;
    __syncthreads();
    int bs = blockIdx.x * EPB;
    int ce = min(EPB, N_EDGES - bs);
    for (int i = t; i < ce; i += 256) {
        int d = ei[N_EDGES + bs + i];
        atomicAdd(&h[d >> BSH], 1);
    }
    __syncthreads();
    for (int i = t; i < NBUCK; i += 256)
        if (h[i]) atomicAdd(&bcnt[i], h[i]);
}

__global__ __launch_bounds__(1024) void k_bscan(const int* __restrict__ bcnt,
                                                int* __restrict__ bptr,
                                                int* __restrict__ bcursor) {
    __shared__ int s[1024];
    const int t = threadIdx.x;
    int v = (t < NBUCK) ? bcnt[t] : 0;
    s[t] = v;
    __syncthreads();
    for (int off = 1; off < 1024; off <<= 1) {
        int u = (t >= off) ? s[t - off] : 0;
        __syncthreads();
        s[t] += u;
        __syncthreads();
    }
    if (t < NBUCK) {
        int excl = s[t] - v;
        bptr[t] = excl;
        bcursor[t] = excl;
        if (t == NBUCK - 1) bptr[NBUCK] = s[t];
    }
}

// LDS-staged binning: packed pairs written in bucket-contiguous runs,
// one global reserve atomic per (block,bucket).
__global__ __launch_bounds__(256) void k_bin(const int* __restrict__ ei,
                                             int* __restrict__ bcursor,
                                             unsigned int* __restrict__ pairs) {
    __shared__ int h[NBUCK];       // counts, then adj (gbase - lscan)
    __shared__ int pos[NBUCK];     // exclusive scan, then bumped during scatter
    __shared__ int partial[256];
    __shared__ int2 stg[EPB];
    const int t = threadIdx.x;
    const int bs = blockIdx.x * EPB;
    const int ce = min(EPB, N_EDGES - bs);

    int sv[16], dv[16];
    #pragma unroll
    for (int i = 0; i < 16; i++) {
        int e = t + i * 256;
        if (e < ce) { sv[i] = ei[bs + e]; dv[i] = ei[N_EDGES + bs + e]; }
        else { sv[i] = 0; dv[i] = -1; }
    }
    for (int i = t; i < NBUCK; i += 256) h[i] = 0;
    __syncthreads();
    #pragma unroll
    for (int i = 0; i < 16; i++)
        if (dv[i] >= 0) atomicAdd(&h[dv[i] >> BSH], 1);
    __syncthreads();

    const int c0 = t * 4;
    int l0 = 0, l1 = 0, l2 = 0, l3 = 0, sum = 0;
    if (c0 < NBUCK) {
        l0 = h[c0]; sum = l0;
        if (c0 + 1 < NBUCK) { l1 = h[c0 + 1]; sum += l1; }
        if (c0 + 2 < NBUCK) { l2 = h[c0 + 2]; sum += l2; }
        if (c0 + 3 < NBUCK) { l3 = h[c0 + 3]; sum += l3; }
    }
    partial[t] = sum;
    __syncthreads();
    for (int off = 1; off < 256; off <<= 1) {
        int u = (t >= off) ? partial[t - off] : 0;
        __syncthreads();
        partial[t] += u;
        __syncthreads();
    }
    int run = partial[t] - sum;
    if (c0 < NBUCK) {
        pos[c0] = run; run += l0;
        if (c0 + 1 < NBUCK) { pos[c0 + 1] = run; run += l1; }
        if (c0 + 2 < NBUCK) { pos[c0 + 2] = run; run += l2; }
        if (c0 + 3 < NBUCK) { pos[c0 + 3] = run; run += l3; }
    }
    __syncthreads();

    for (int b = t; b < NBUCK; b += 256) {
        int cnt = h[b];
        if (cnt > 0) {
            int g = atomicAdd(&bcursor[b], cnt);
            h[b] = g - pos[b];
        }
    }
    __syncthreads();

    #pragma unroll
    for (int i = 0; i < 16; i++) {
        if (dv[i] >= 0) {
            int b = dv[i] >> BSH;
            int p = atomicAdd(&pos[b], 1);
            stg[p] = make_int2(sv[i], dv[i]);
        }
    }
    __syncthreads();

    for (int j = t; j < ce; j += 256) {
        int2 pr = stg[j];
        pairs[j + h[pr.y >> BSH]] =
            ((unsigned int)pr.x << 7) | (unsigned int)(pr.y & (BROWS - 1));
    }
}

// ---------------- per-bucket exact counting sort -> CSR (row_ptr, sorted_src) ----------------

__global__ __launch_bounds__(256) void k_sort(const unsigned int* __restrict__ pairs,
                                              const int* __restrict__ bptr,
                                              int* __restrict__ row_ptr,
                                              int* __restrict__ sorted_src) {
    __shared__ int hist[BROWS];
    __shared__ int pos[BROWS];
    const int t = threadIdx.x;
    const int b = blockIdx.x;
    const int nbase = b << BSH;
    const int start = bptr[b], end = bptr[b + 1];

    if (t < BROWS) hist[t] = 0;
    __syncthreads();
    for (int e = start + t; e < end; e += 256) {
        atomicAdd(&hist[pairs[e] & (BROWS - 1)], 1);
    }
    __syncthreads();
    if (t < BROWS) pos[t] = hist[t];
    __syncthreads();
    for (int off = 1; off < BROWS; off <<= 1) {
        int v = 0;
        if (t < BROWS && t >= off) v = pos[t - off];
        __syncthreads();
        if (t < BROWS) pos[t] += v;
        __syncthreads();
    }
    if (t < BROWS) {
        int rp = start + pos[t] - hist[t];
        int n = nbase + t;
        if (n < N_NODES) row_ptr[n] = rp;
        pos[t] = rp;
    }
    if (b == 0 && t == 0) row_ptr[N_NODES] = N_EDGES;
    __syncthreads();
    for (int e = start + t; e < end; e += 256) {
        unsigned int p = pairs[e];
        int idx = atomicAdd(&pos[p & (BROWS - 1)], 1);
        sorted_src[idx] = (int)(p >> 7);
    }
}

// ---------------- conv1 front: t1 = x@W1 (fp32), t2 = relu(x)@W1 (fp16) ----------------

__global__ __launch_bounds__(256) void k_g1(const float* __restrict__ x,
                                            const float* __restrict__ W1,
                                            float* __restrict__ t1,
                                            __half* __restrict__ t2) {
    __shared__ float sX[64 * PADK];
    __shared__ float sW[DIM * PADK];   // W1^T: [col][k]
    const int t = threadIdx.x;
    const int base = blockIdx.x * 64;

    for (int idx = t; idx < N_FEAT * DIM; idx += 256) {
        int k = idx / DIM, c = idx - k * DIM;
        sW[c * PADK + k] = W1[idx];
    }
    for (int idx = t; idx < 64 * 32; idx += 256) {
        int row = idx >> 5, kq = idx & 31;
        float4 v = make_float4(0.f, 0.f, 0.f, 0.f);
        if (base + row < N_NODES) v = ((const float4*)x)[(base + row) * 32 + kq];
        *(float4*)&sX[row * PADK + kq * 4] = v;
    }
    __syncthreads();

    const int cg = t & 7;
    const int rg = t >> 3;
    const int r0 = rg * 2;
    const int c0 = cg * 6;

    float a1[2][6], a2[2][6];
    #pragma unroll
    for (int r = 0; r < 2; r++)
        #pragma unroll
        for (int c = 0; c < 6; c++) { a1[r][c] = 0.f; a2[r][c] = 0.f; }

    #pragma unroll 2
    for (int kq = 0; kq < 32; kq++) {
        float4 x0 = *(const float4*)&sX[(r0 + 0) * PADK + kq * 4];
        float4 x1 = *(const float4*)&sX[(r0 + 1) * PADK + kq * 4];
        float4 p0 = make_float4(fmaxf(x0.x, 0.f), fmaxf(x0.y, 0.f), fmaxf(x0.z, 0.f), fmaxf(x0.w, 0.f));
        float4 p1 = make_float4(fmaxf(x1.x, 0.f), fmaxf(x1.y, 0.f), fmaxf(x1.z, 0.f), fmaxf(x1.w, 0.f));
        #pragma unroll
        for (int c = 0; c < 6; c++) {
            float4 w = *(const float4*)&sW[(c0 + c) * PADK + kq * 4];
            a1[0][c] += x0.x * w.x + x0.y * w.y + x0.z * w.z + x0.w * w.w;
            a1[1][c] += x1.x * w.x + x1.y * w.y + x1.z * w.z + x1.w * w.w;
            a2[0][c] += p0.x * w.x + p0.y * w.y + p0.z * w.z + p0.w * w.w;
            a2[1][c] += p1.x * w.x + p1.y * w.y + p1.z * w.z + p1.w * w.w;
        }
    }

    #pragma unroll
    for (int r = 0; r < 2; r++) {
        int gr = base + r0 + r;
        if (gr < N_NODES) {
            #pragma unroll
            for (int c = 0; c < 3; c++) {
                *(float2*)&t1[gr * DIM + c0 + 2 * c] = make_float2(a1[r][2 * c], a1[r][2 * c + 1]);
                *(__half2*)&t2[gr * DIM + c0 + 2 * c] =
                    __float22half2_rn(make_float2(a2[r][2 * c], a2[r][2 * c + 1]));
            }
        }
    }
}

// ---------------- aggregation: out = relu(tlin + segsum(tmsg_fp16) + bias) ----------------
// One wave per node; lanes 0..23 each own 2 features (half2 gather, float2 acc).
// out aliases tlin: read-before-write, same thread, row-exclusive.

__global__ __launch_bounds__(256) void k_aggr(const float* tlin,
                                              const __half2* __restrict__ tmsg,  // [N][24]
                                              const int* __restrict__ row_ptr,
                                              const int* __restrict__ ssrc,
                                              const float* __restrict__ bias,
                                              float* out) {
    int n = blockIdx.x * 4 + (threadIdx.x >> 6);
    int lane = threadIdx.x & 63;
    if (n >= N_NODES) return;
    int start = row_ptr[n], end = row_ptr[n + 1];
    bool act = lane < 24;
    float ax = 0.f, ay = 0.f;
    int e = start;
    for (; e + 8 <= end; e += 8) {
        int s0 = ssrc[e], s1 = ssrc[e + 1], s2 = ssrc[e + 2], s3 = ssrc[e + 3];
        int s4 = ssrc[e + 4], s5 = ssrc[e + 5], s6 = ssrc[e + 6], s7 = ssrc[e + 7];
        if (act) {
            float2 v0 = __half22float2(tmsg[s0 * 24 + lane]);
            float2 v1 = __half22float2(tmsg[s1 * 24 + lane]);
            float2 v2 = __half22float2(tmsg[s2 * 24 + lane]);
            float2 v3 = __half22float2(tmsg[s3 * 24 + lane]);
            float2 v4 = __half22float2(tmsg[s4 * 24 + lane]);
            float2 v5 = __half22float2(tmsg[s5 * 24 + lane]);
            float2 v6 = __half22float2(tmsg[s6 * 24 + lane]);
            float2 v7 = __half22float2(tmsg[s7 * 24 + lane]);
            ax += ((v0.x + v1.x) + (v2.x + v3.x)) + ((v4.x + v5.x) + (v6.x + v7.x));
            ay += ((v0.y + v1.y) + (v2.y + v3.y)) + ((v4.y + v5.y) + (v6.y + v7.y));
        }
    }
    for (; e < end; e++) {
        int s = ssrc[e];
        if (act) {
            float2 v = __half22float2(tmsg[s * 24 + lane]);
            ax += v.x; ay += v.y;
        }
    }
    if (act) {
        float2 base = ((const float2*)tlin)[n * 24 + lane];
        float2 bi = ((const float2*)bias)[lane];
        float vx = fmaxf(base.x + ax + bi.x, 0.f);
        float vy = fmaxf(base.y + ay + bi.y, 0.f);
        ((float2*)out)[n * 24 + lane] = make_float2(vx, vy);
    }
}

// ---------------- chain1: v=u@c1W2+b2; g1=bn1(relu(v)); t3=g1@c2W1 (fp32); t4=relu(g1)@c2W1 (fp16) ----------------
// t3 aliases u: u fully staged to LDS before first sync; writes after; row-exclusive.

__global__ __launch_bounds__(256) void k_chain1(const float* u,
                                                const float* __restrict__ W2,
                                                const float* __restrict__ b2,
                                                const float* __restrict__ bng,
                                                const float* __restrict__ bnb,
                                                const float* __restrict__ bnm,
                                                const float* __restrict__ bnv,
                                                const float* __restrict__ W1n,
                                                float* t3,
                                                __half* __restrict__ t4) {
    __shared__ float sU[64 * PADD];
    __shared__ float sG[64 * PADD];
    __shared__ float sW2[DIM * PADD];
    __shared__ float sW1[DIM * PADD];
    const int t = threadIdx.x;
    const int base = blockIdx.x * 64;

    for (int idx = t; idx < DIM * DIM; idx += 256) {
        int k = idx / DIM, c = idx - k * DIM;
        sW2[c * PADD + k] = W2[idx];
        sW1[c * PADD + k] = W1n[idx];
    }
    for (int idx = t; idx < 64 * 12; idx += 256) {
        int row = idx / 12, kq = idx - row * 12;
        float4 v = make_float4(0.f, 0.f, 0.f, 0.f);
        if (base + row < N_NODES) v = ((const float4*)u)[(base + row) * 12 + kq];
        *(float4*)&sU[row * PADD + kq * 4] = v;
    }
    __syncthreads();

    const int cg = t & 7, rg = t >> 3;
    const int r0 = rg * 2, c0 = cg * 6;

    {
        float g[2][6];
        #pragma unroll
        for (int r = 0; r < 2; r++)
            #pragma unroll
            for (int c = 0; c < 6; c++) g[r][c] = 0.f;

        #pragma unroll 2
        for (int kq = 0; kq < 12; kq++) {
            float4 x0 = *(const float4*)&sU[(r0 + 0) * PADD + kq * 4];
            float4 x1 = *(const float4*)&sU[(r0 + 1) * PADD + kq * 4];
            #pragma unroll
            for (int c = 0; c < 6; c++) {
                float4 w = *(const float4*)&sW2[(c0 + c) * PADD + kq * 4];
                g[0][c] += x0.x * w.x + x0.y * w.y + x0.z * w.z + x0.w * w.w;
                g[1][c] += x1.x * w.x + x1.y * w.y + x1.z * w.z + x1.w * w.w;
            }
        }
        #pragma unroll
        for (int c = 0; c < 6; c++) {
            float bb = b2[c0 + c];
            float sc = bng[c0 + c] * rsqrtf(bnv[c0 + c] + BN_EPS);
            float sh = bnb[c0 + c] - bnm[c0 + c] * sc;
            #pragma unroll
            for (int r = 0; r < 2; r++) {
                float rl = fmaxf(g[r][c] + bb, 0.f);
                sG[(r0 + r) * PADD + c0 + c] = rl * sc + sh;
            }
        }
    }
    __syncthreads();

    {
        float a3[2][6], a4[2][6];
        #pragma unroll
        for (int r = 0; r < 2; r++)
            #pragma unroll
            for (int c = 0; c < 6; c++) { a3[r][c] = 0.f; a4[r][c] = 0.f; }

        #pragma unroll 2
        for (int kq = 0; kq < 12; kq++) {
            float4 x0 = *(const float4*)&sG[(r0 + 0) * PADD + kq * 4];
            float4 x1 = *(const float4*)&sG[(r0 + 1) * PADD + kq * 4];
            float4 p0 = make_float4(fmaxf(x0.x, 0.f), fmaxf(x0.y, 0.f), fmaxf(x0.z, 0.f), fmaxf(x0.w, 0.f));
            float4 p1 = make_float4(fmaxf(x1.x, 0.f), fmaxf(x1.y, 0.f), fmaxf(x1.z, 0.f), fmaxf(x1.w, 0.f));
            #pragma unroll
            for (int c = 0; c < 6; c++) {
                float4 w = *(const float4*)&sW1[(c0 + c) * PADD + kq * 4];
                a3[0][c] += x0.x * w.x + x0.y * w.y + x0.z * w.z + x0.w * w.w;
                a3[1][c] += x1.x * w.x + x1.y * w.y + x1.z * w.z + x1.w * w.w;
                a4[0][c] += p0.x * w.x + p0.y * w.y + p0.z * w.z + p0.w * w.w;
                a4[1][c] += p1.x * w.x + p1.y * w.y + p1.z * w.z + p1.w * w.w;
            }
        }
        #pragma unroll
        for (int r = 0; r < 2; r++) {
            int gr = base + r0 + r;
            if (gr < N_NODES) {
                #pragma unroll
                for (int c = 0; c < 3; c++) {
                    *(float2*)&t3[gr * DIM + c0 + 2 * c] = make_float2(a3[r][2 * c], a3[r][2 * c + 1]);
                    *(__half2*)&t4[gr * DIM + c0 + 2 * c] =
                        __float22half2_rn(make_float2(a4[r][2 * c], a4[r][2 * c + 1]));
                }
            }
        }
    }
}

// ---------------- chain2: v2=u2@c2W2+b2; g2=bn2(relu); z=relu(g2@fc1+b); out=z@fc2+b ----------------

__global__ __launch_bounds__(256) void k_chain2(const float* __restrict__ u2,
                                                const float* __restrict__ W2,
                                                const float* __restrict__ b2,
                                                const float* __restrict__ bng,
                                                const float* __restrict__ bnb,
                                                const float* __restrict__ bnm,
                                                const float* __restrict__ bnv,
                                                const float* __restrict__ fc1W,
                                                const float* __restrict__ fc1b,
                                                const float* __restrict__ fc2W,
                                                const float* __restrict__ fc2b,
                                                float* __restrict__ out) {
    __shared__ float sA[64 * PADD];
    __shared__ float sB[64 * PADD];
    __shared__ float sWa[DIM * PADD];
    __shared__ float sWb[DIM * PADD];
    __shared__ float sWc[N_CLASS * PADD];
    const int t = threadIdx.x;
    const int base = blockIdx.x * 64;

    for (int idx = t; idx < DIM * DIM; idx += 256) {
        int k = idx / DIM, c = idx - k * DIM;
        sWa[c * PADD + k] = W2[idx];
        sWb[c * PADD + k] = fc1W[idx];
    }
    for (int idx = t; idx < DIM * N_CLASS; idx += 256) {
        int k = idx / N_CLASS, c = idx - k * N_CLASS;
        sWc[c * PADD + k] = fc2W[idx];
    }
    for (int idx = t; idx < 64 * 12; idx += 256) {
        int row = idx / 12, kq = idx - row * 12;
        float4 v = make_float4(0.f, 0.f, 0.f, 0.f);
        if (base + row < N_NODES) v = ((const float4*)u2)[(base + row) * 12 + kq];
        *(float4*)&sA[row * PADD + kq * 4] = v;
    }
    __syncthreads();

    const int cg = t & 7, rg = t >> 3;
    const int r0 = rg * 2, c0 = cg * 6;

    {
        float g[2][6];
        #pragma unroll
        for (int r = 0; r < 2; r++)
            #pragma unroll
            for (int c = 0; c < 6; c++) g[r][c] = 0.f;
        #pragma unroll 2
        for (int kq = 0; kq < 12; kq++) {
            float4 x0 = *(const float4*)&sA[(r0 + 0) * PADD + kq * 4];
            float4 x1 = *(const float4*)&sA[(r0 + 1) * PADD + kq * 4];
            #pragma unroll
            for (int c = 0; c < 6; c++) {
                float4 w = *(const float4*)&sWa[(c0 + c) * PADD + kq * 4];
                g[0][c] += x0.x * w.x + x0.y * w.y + x0.z * w.z + x0.w * w.w;
                g[1][c] += x1.x * w.x + x1.y * w.y + x1.z * w.z + x1.w * w.w;
            }
        }
        #pragma unroll
        for (int c = 0; c < 6; c++) {
            float bb = b2[c0 + c];
            float sc = bng[c0 + c] * rsqrtf(bnv[c0 + c] + BN_EPS);
            float sh = bnb[c0 + c] - bnm[c0 + c] * sc;
            #pragma unroll
            for (int r = 0; r < 2; r++) {
                float rl = fmaxf(g[r][c] + bb, 0.f);
                sB[(r0 + r) * PADD + c0 + c] = rl * sc + sh;
            }
        }
    }
    __syncthreads();

    {
        float z[2][6];
        #pragma unroll
        for (int r = 0; r < 2; r++)
            #pragma unroll
            for (int c = 0; c < 6; c++) z[r][c] = 0.f;
        #pragma unroll 2
        for (int kq = 0; kq < 12; kq++) {
            float4 x0 = *(const float4*)&sB[(r0 + 0) * PADD + kq * 4];
            float4 x1 = *(const float4*)&sB[(r0 + 1) * PADD + kq * 4];
            #pragma unroll
            for (int c = 0; c < 6; c++) {
                float4 w = *(const float4*)&sWb[(c0 + c) * PADD + kq * 4];
                z[0][c] += x0.x * w.x + x0.y * w.y + x0.z * w.z + x0.w * w.w;
                z[1][c] += x1.x * w.x + x1.y * w.y + x1.z * w.z + x1.w * w.w;
            }
        }
        __syncthreads();
        #pragma unroll
        for (int c = 0; c < 6; c++) {
            float bb = fc1b[c0 + c];
            #pragma unroll
            for (int r = 0; r < 2; r++)
                sA[(r0 + r) * PADD + c0 + c] = fmaxf(z[r][c] + bb, 0.f);
        }
    }
    __syncthreads();

    if (cg < 6) {
        const int cc0 = cg * 3;
        float o[2][3];
        #pragma unroll
        for (int r = 0; r < 2; r++)
            #pragma unroll
            for (int c = 0; c < 3; c++) o[r][c] = 0.f;
        #pragma unroll 2
        for (int kq = 0; kq < 12; kq++) {
            float4 x0 = *(const float4*)&sA[(r0 + 0) * PADD + kq * 4];
            float4 x1 = *(const float4*)&sA[(r0 + 1) * PADD + kq * 4];
            #pragma unroll
            for (int c = 0; c < 3; c++) {
                float4 w = *(const float4*)&sWc[(cc0 + c) * PADD + kq * 4];
                o[0][c] += x0.x * w.x + x0.y * w.y + x0.z * w.z + x0.w * w.w;
                o[1][c] += x1.x * w.x + x1.y * w.y + x1.z * w.z + x1.w * w.w;
            }
        }
        #pragma unroll
        for (int r = 0; r < 2; r++) {
            int gr = base + r0 + r;
            if (gr < N_NODES) {
                #pragma unroll
                for (int c = 0; c < 3; c++)
                    out[gr * N_CLASS + cc0 + c] = o[r][c] + fc2b[cc0 + c];
            }
        }
    }
}

// ---------------- launch ----------------

extern "C" void kernel_launch(void* const* d_in, const int* in_sizes, int n_in,
                              void* d_out, int out_size, void* d_ws, size_t ws_size,
                              hipStream_t stream) {
    const float* x     = (const float*)d_in[0];
    const int*   ei    = (const int*)d_in[1];
    const float* c1_W1 = (const float*)d_in[2];
    const float* c1_b1 = (const float*)d_in[3];
    const float* c1_W2 = (const float*)d_in[4];
    const float* c1_b2 = (const float*)d_in[5];
    const float* c2_W1 = (const float*)d_in[6];
    const float* c2_b1 = (const float*)d_in[7];
    const float* c2_W2 = (const float*)d_in[8];
    const float* c2_b2 = (const float*)d_in[9];
    const float* bn1_g = (const float*)d_in[10];
    const float* bn1_b = (const float*)d_in[11];
    const float* bn1_m = (const float*)d_in[12];
    const float* bn1_v = (const float*)d_in[13];
    const float* bn2_g = (const float*)d_in[14];
    const float* bn2_b = (const float*)d_in[15];
    const float* bn2_m = (const float*)d_in[16];
    const float* bn2_v = (const float*)d_in[17];
    const float* fc1_W = (const float*)d_in[18];
    const float* fc1_b = (const float*)d_in[19];
    const float* fc2_W = (const float*)d_in[20];
    const float* fc2_b = (const float*)d_in[21];
    float* out = (float*)d_out;

    char* ws = (char*)d_ws;
    size_t o = 0;
    auto take = [&](size_t bytes) {
        void* p = ws + o;
        o = (o + bytes + 255) & ~(size_t)255;
        return p;
    };
    unsigned int* pairs = (unsigned int*)take((size_t)N_EDGES * 4);   // 12.8 MB (packed)
    int*  sorted_src    = (int*)take((size_t)N_EDGES * 4);            // 12.8 MB
    int*  row_ptr       = (int*)take((size_t)(N_NODES + 1) * 4);
    int*  bcnt          = (int*)take((size_t)NBUCK * 4);
    int*  bptr          = (int*)take((size_t)(NBUCK + 1) * 4);
    int*  bcursor       = (int*)take((size_t)NBUCK * 4);
    float*  t1          = (float*)take((size_t)N_NODES * DIM * 4);    // aliased: t1/u/t3/u2 (fp32)
    __half* t2h         = (__half*)take((size_t)N_NODES * DIM * 2);   // t2/t4 (fp16 messages)
    (void)ws_size; (void)in_sizes; (void)n_in; (void)out_size;

    const int NB64 = (N_NODES + 63) / 64;   // 1563
    const int NB4  = (N_NODES + 3) / 4;     // 25000

    hipMemsetAsync(bcnt, 0, (size_t)NBUCK * 4, stream);
    k_bhist<<<NBLK_E, 256, 0, stream>>>(ei, bcnt);
    k_bscan<<<1, 1024, 0, stream>>>(bcnt, bptr, bcursor);
    k_bin<<<NBLK_E, 256, 0, stream>>>(ei, bcursor, pairs);
    k_sort<<<NBUCK, 256, 0, stream>>>(pairs, bptr, row_ptr, sorted_src);

    k_g1<<<NB64, 256, 0, stream>>>(x, c1_W1, t1, t2h);
    k_aggr<<<NB4, 256, 0, stream>>>(t1, (const __half2*)t2h, row_ptr, sorted_src, c1_b1, t1);
    k_chain1<<<NB64, 256, 0, stream>>>(t1, c1_W2, c1_b2, bn1_g, bn1_b, bn1_m, bn1_v,
                                       c2_W1, t1, t2h);
    k_aggr<<<NB4, 256, 0, stream>>>(t1, (const __half2*)t2h, row_ptr, sorted_src, c2_b1, t1);
    k_chain2<<<NB64, 256, 0, stream>>>(t1, c2_W2, c2_b2, bn2_g, bn2_b, bn2_m, bn2_v,
                                       fc1_W, fc1_b, fc2_W, fc2_b, out);
}

// Round 7
// 349.928 us; speedup vs baseline: 6.3308x; 1.1683x over previous
//
#include <hip/hip_runtime.h>
#include <hip/hip_fp16.h>

#define N_NODES 100000
#define N_EDGES 3200000
#define N_FEAT  128
#define DIM     48
#define N_CLASS 18
#define BN_EPS  1e-5f

#define PADK 132   // x-tile row stride (dwords); 132%32=4 -> 2-way bank alias (free)
#define PADD 52    // 48-wide tile row stride; 52%32=20 -> 2-way bank alias (free)

#define BSH    7                                   // bucket = dst >> 7 (128 nodes)
#define BROWS  128                                 // nodes per bucket
#define NBUCK  ((N_NODES + BROWS - 1) / BROWS)     // 782
#define EPB    4096                                // edges per binning block
#define NBLK_E ((N_EDGES + EPB - 1) / EPB)         // 782

// packed edge: (src << 7) | (dst & 127).  src < 2^17, fits 24 bits.

// ---------------- bucket-granular edge preprocessing ----------------

__global__ __launch_bounds__(256) void k_bhist(const int* __restrict__ ei,
                                               int* __restrict__ bcnt) {
    __shared__ int h[NBUCK];
    const int t = threadIdx.x;
    for (int i = t; i < NBUCK; i += 256) h[i] = 0;
    __syncthreads();
    int bs = blockIdx.x * EPB;
    int ce = min(EPB, N_EDGES - bs);
    for (int i = t; i < ce; i += 256) {
        int d = ei[N_EDGES + bs + i];
        atomicAdd(&h[d >> BSH], 1);
    }
    __syncthreads();
    for (int i = t; i < NBUCK; i += 256)
        if (h[i]) atomicAdd(&bcnt[i], h[i]);
}

__global__ __launch_bounds__(1024) void k_bscan(const int* __restrict__ bcnt,
                                                int* __restrict__ bptr,
                                                int* __restrict__ bcursor) {
    __shared__ int s[1024];
    const int t = threadIdx.x;
    int v = (t < NBUCK) ? bcnt[t] : 0;
    s[t] = v;
    __syncthreads();
    for (int off = 1; off < 1024; off <<= 1) {
        int u = (t >= off) ? s[t - off] : 0;
        __syncthreads();
        s[t] += u;
        __syncthreads();
    }
    if (t < NBUCK) {
        int excl = s[t] - v;
        bptr[t] = excl;
        bcursor[t] = excl;
        if (t == NBUCK - 1) bptr[NBUCK] = s[t];
    }
}

// LDS-staged binning: packed pairs written in bucket-contiguous runs,
// one global reserve atomic per (block,bucket).
__global__ __launch_bounds__(256) void k_bin(const int* __restrict__ ei,
                                             int* __restrict__ bcursor,
                                             unsigned int* __restrict__ pairs) {
    __shared__ int h[NBUCK];       // counts, then adj (gbase - lscan)
    __shared__ int pos[NBUCK];     // exclusive scan, then bumped during scatter
    __shared__ int partial[256];
    __shared__ int2 stg[EPB];
    const int t = threadIdx.x;
    const int bs = blockIdx.x * EPB;
    const int ce = min(EPB, N_EDGES - bs);

    int sv[16], dv[16];
    #pragma unroll
    for (int i = 0; i < 16; i++) {
        int e = t + i * 256;
        if (e < ce) { sv[i] = ei[bs + e]; dv[i] = ei[N_EDGES + bs + e]; }
        else { sv[i] = 0; dv[i] = -1; }
    }
    for (int i = t; i < NBUCK; i += 256) h[i] = 0;
    __syncthreads();
    #pragma unroll
    for (int i = 0; i < 16; i++)
        if (dv[i] >= 0) atomicAdd(&h[dv[i] >> BSH], 1);
    __syncthreads();

    const int c0 = t * 4;
    int l0 = 0, l1 = 0, l2 = 0, l3 = 0, sum = 0;
    if (c0 < NBUCK) {
        l0 = h[c0]; sum = l0;
        if (c0 + 1 < NBUCK) { l1 = h[c0 + 1]; sum += l1; }
        if (c0 + 2 < NBUCK) { l2 = h[c0 + 2]; sum += l2; }
        if (c0 + 3 < NBUCK) { l3 = h[c0 + 3]; sum += l3; }
    }
    partial[t] = sum;
    __syncthreads();
    for (int off = 1; off < 256; off <<= 1) {
        int u = (t >= off) ? partial[t - off] : 0;
        __syncthreads();
        partial[t] += u;
        __syncthreads();
    }
    int run = partial[t] - sum;
    if (c0 < NBUCK) {
        pos[c0] = run; run += l0;
        if (c0 + 1 < NBUCK) { pos[c0 + 1] = run; run += l1; }
        if (c0 + 2 < NBUCK) { pos[c0 + 2] = run; run += l2; }
        if (c0 + 3 < NBUCK) { pos[c0 + 3] = run; run += l3; }
    }
    __syncthreads();

    for (int b = t; b < NBUCK; b += 256) {
        int cnt = h[b];
        if (cnt > 0) {
            int g = atomicAdd(&bcursor[b], cnt);
            h[b] = g - pos[b];
        }
    }
    __syncthreads();

    #pragma unroll
    for (int i = 0; i < 16; i++) {
        if (dv[i] >= 0) {
            int b = dv[i] >> BSH;
            int p = atomicAdd(&pos[b], 1);
            stg[p] = make_int2(sv[i], dv[i]);
        }
    }
    __syncthreads();

    for (int j = t; j < ce; j += 256) {
        int2 pr = stg[j];
        pairs[j + h[pr.y >> BSH]] =
            ((unsigned int)pr.x << 7) | (unsigned int)(pr.y & (BROWS - 1));
    }
}

// ---------------- per-bucket exact counting sort -> CSR (row_ptr, sorted_src) ----------------

__global__ __launch_bounds__(256) void k_sort(const unsigned int* __restrict__ pairs,
                                              const int* __restrict__ bptr,
                                              int* __restrict__ row_ptr,
                                              int* __restrict__ sorted_src) {
    __shared__ int hist[BROWS];
    __shared__ int pos[BROWS];
    const int t = threadIdx.x;
    const int b = blockIdx.x;
    const int nbase = b << BSH;
    const int start = bptr[b], end = bptr[b + 1];

    if (t < BROWS) hist[t] = 0;
    __syncthreads();
    for (int e = start + t; e < end; e += 256) {
        atomicAdd(&hist[pairs[e] & (BROWS - 1)], 1);
    }
    __syncthreads();
    if (t < BROWS) pos[t] = hist[t];
    __syncthreads();
    for (int off = 1; off < BROWS; off <<= 1) {
        int v = 0;
        if (t < BROWS && t >= off) v = pos[t - off];
        __syncthreads();
        if (t < BROWS) pos[t] += v;
        __syncthreads();
    }
    if (t < BROWS) {
        int rp = start + pos[t] - hist[t];
        int n = nbase + t;
        if (n < N_NODES) row_ptr[n] = rp;
        pos[t] = rp;
    }
    if (b == 0 && t == 0) row_ptr[N_NODES] = N_EDGES;
    __syncthreads();
    for (int e = start + t; e < end; e += 256) {
        unsigned int p = pairs[e];
        int idx = atomicAdd(&pos[p & (BROWS - 1)], 1);
        sorted_src[idx] = (int)(p >> 7);
    }
}

// ---------------- conv1 front: t1 = x@W1 (fp32), t2 = relu(x)@W1 (fp16) ----------------

__global__ __launch_bounds__(256) void k_g1(const float* __restrict__ x,
                                            const float* __restrict__ W1,
                                            float* __restrict__ t1,
                                            __half* __restrict__ t2) {
    __shared__ float sX[64 * PADK];
    __shared__ float sW[DIM * PADK];   // W1^T: [col][k]
    const int t = threadIdx.x;
    const int base = blockIdx.x * 64;

    for (int idx = t; idx < N_FEAT * DIM; idx += 256) {
        int k = idx / DIM, c = idx - k * DIM;
        sW[c * PADK + k] = W1[idx];
    }
    for (int idx = t; idx < 64 * 32; idx += 256) {
        int row = idx >> 5, kq = idx & 31;
        float4 v = make_float4(0.f, 0.f, 0.f, 0.f);
        if (base + row < N_NODES) v = ((const float4*)x)[(base + row) * 32 + kq];
        *(float4*)&sX[row * PADK + kq * 4] = v;
    }
    __syncthreads();

    const int cg = t & 7;
    const int rg = t >> 3;
    const int r0 = rg * 2;
    const int c0 = cg * 6;

    float a1[2][6], a2[2][6];
    #pragma unroll
    for (int r = 0; r < 2; r++)
        #pragma unroll
        for (int c = 0; c < 6; c++) { a1[r][c] = 0.f; a2[r][c] = 0.f; }

    #pragma unroll 2
    for (int kq = 0; kq < 32; kq++) {
        float4 x0 = *(const float4*)&sX[(r0 + 0) * PADK + kq * 4];
        float4 x1 = *(const float4*)&sX[(r0 + 1) * PADK + kq * 4];
        float4 p0 = make_float4(fmaxf(x0.x, 0.f), fmaxf(x0.y, 0.f), fmaxf(x0.z, 0.f), fmaxf(x0.w, 0.f));
        float4 p1 = make_float4(fmaxf(x1.x, 0.f), fmaxf(x1.y, 0.f), fmaxf(x1.z, 0.f), fmaxf(x1.w, 0.f));
        #pragma unroll
        for (int c = 0; c < 6; c++) {
            float4 w = *(const float4*)&sW[(c0 + c) * PADK + kq * 4];
            a1[0][c] += x0.x * w.x + x0.y * w.y + x0.z * w.z + x0.w * w.w;
            a1[1][c] += x1.x * w.x + x1.y * w.y + x1.z * w.z + x1.w * w.w;
            a2[0][c] += p0.x * w.x + p0.y * w.y + p0.z * w.z + p0.w * w.w;
            a2[1][c] += p1.x * w.x + p1.y * w.y + p1.z * w.z + p1.w * w.w;
        }
    }

    #pragma unroll
    for (int r = 0; r < 2; r++) {
        int gr = base + r0 + r;
        if (gr < N_NODES) {
            #pragma unroll
            for (int c = 0; c < 3; c++) {
                *(float2*)&t1[gr * DIM + c0 + 2 * c] = make_float2(a1[r][2 * c], a1[r][2 * c + 1]);
                *(__half2*)&t2[gr * DIM + c0 + 2 * c] =
                    __float22half2_rn(make_float2(a2[r][2 * c], a2[r][2 * c + 1]));
            }
        }
    }
}

// ---------------- aggregation: out = relu(tlin + segsum(tmsg_fp16) + bias) ----------------
// 5 nodes per wave: 12 lanes per node, each lane gathers 8B (4 halfs) of the
// 96B message row -> one VMEM instruction serves 5 edges (5x MLP vs 1 node/wave).
// out aliases tlin: read-before-write, same thread, row-exclusive.

__device__ inline float2 h2tof2(unsigned int u) {
    __half2 h = *reinterpret_cast<__half2*>(&u);
    return __half22float2(h);
}

__global__ __launch_bounds__(256) void k_aggr(const float* tlin,
                                              const uint2* __restrict__ tmsg8,  // [N][12] 8B chunks
                                              const int* __restrict__ row_ptr,
                                              const int* __restrict__ ssrc,
                                              const float* __restrict__ bias,
                                              float* out) {
    const int t = threadIdx.x;
    const int wid = t >> 6, lane = t & 63;
    const int sub = lane / 12;          // 0..5 (5 == idle lanes 60-63)
    const int fl  = lane - sub * 12;    // 0..11 -> features fl*4 .. fl*4+3
    int n = blockIdx.x * 20 + wid * 5 + sub;
    const bool act = (sub < 5) && (n < N_NODES);
    int start = 0, end = 0;
    if (act) { start = row_ptr[n]; end = row_ptr[n + 1]; }

    float ax = 0.f, ay = 0.f, az = 0.f, aw = 0.f;
    int e = start;
    for (; e + 8 <= end; e += 8) {
        int s0 = ssrc[e], s1 = ssrc[e + 1], s2 = ssrc[e + 2], s3 = ssrc[e + 3];
        int s4 = ssrc[e + 4], s5 = ssrc[e + 5], s6 = ssrc[e + 6], s7 = ssrc[e + 7];
        uint2 v0 = tmsg8[s0 * 12 + fl];
        uint2 v1 = tmsg8[s1 * 12 + fl];
        uint2 v2 = tmsg8[s2 * 12 + fl];
        uint2 v3 = tmsg8[s3 * 12 + fl];
        uint2 v4 = tmsg8[s4 * 12 + fl];
        uint2 v5 = tmsg8[s5 * 12 + fl];
        uint2 v6 = tmsg8[s6 * 12 + fl];
        uint2 v7 = tmsg8[s7 * 12 + fl];
        float2 f;
        f = h2tof2(v0.x); ax += f.x; ay += f.y;  f = h2tof2(v0.y); az += f.x; aw += f.y;
        f = h2tof2(v1.x); ax += f.x; ay += f.y;  f = h2tof2(v1.y); az += f.x; aw += f.y;
        f = h2tof2(v2.x); ax += f.x; ay += f.y;  f = h2tof2(v2.y); az += f.x; aw += f.y;
        f = h2tof2(v3.x); ax += f.x; ay += f.y;  f = h2tof2(v3.y); az += f.x; aw += f.y;
        f = h2tof2(v4.x); ax += f.x; ay += f.y;  f = h2tof2(v4.y); az += f.x; aw += f.y;
        f = h2tof2(v5.x); ax += f.x; ay += f.y;  f = h2tof2(v5.y); az += f.x; aw += f.y;
        f = h2tof2(v6.x); ax += f.x; ay += f.y;  f = h2tof2(v6.y); az += f.x; aw += f.y;
        f = h2tof2(v7.x); ax += f.x; ay += f.y;  f = h2tof2(v7.y); az += f.x; aw += f.y;
    }
    for (; e < end; e++) {
        int s = ssrc[e];
        uint2 v = tmsg8[s * 12 + fl];
        float2 f;
        f = h2tof2(v.x); ax += f.x; ay += f.y;
        f = h2tof2(v.y); az += f.x; aw += f.y;
    }
    if (act) {
        float4 base = ((const float4*)tlin)[n * 12 + fl];
        float4 bi   = ((const float4*)bias)[fl];
        float4 r;
        r.x = fmaxf(base.x + ax + bi.x, 0.f);
        r.y = fmaxf(base.y + ay + bi.y, 0.f);
        r.z = fmaxf(base.z + az + bi.z, 0.f);
        r.w = fmaxf(base.w + aw + bi.w, 0.f);
        ((float4*)out)[n * 12 + fl] = r;
    }
}

// ---------------- chain1: v=u@c1W2+b2; g1=bn1(relu(v)); t3=g1@c2W1 (fp32); t4=relu(g1)@c2W1 (fp16) ----------------
// t3 aliases u: u fully staged to LDS before first sync; writes after; row-exclusive.

__global__ __launch_bounds__(256) void k_chain1(const float* u,
                                                const float* __restrict__ W2,
                                                const float* __restrict__ b2,
                                                const float* __restrict__ bng,
                                                const float* __restrict__ bnb,
                                                const float* __restrict__ bnm,
                                                const float* __restrict__ bnv,
                                                const float* __restrict__ W1n,
                                                float* t3,
                                                __half* __restrict__ t4) {
    __shared__ float sU[64 * PADD];
    __shared__ float sG[64 * PADD];
    __shared__ float sW2[DIM * PADD];
    __shared__ float sW1[DIM * PADD];
    const int t = threadIdx.x;
    const int base = blockIdx.x * 64;

    for (int idx = t; idx < DIM * DIM; idx += 256) {
        int k = idx / DIM, c = idx - k * DIM;
        sW2[c * PADD + k] = W2[idx];
        sW1[c * PADD + k] = W1n[idx];
    }
    for (int idx = t; idx < 64 * 12; idx += 256) {
        int row = idx / 12, kq = idx - row * 12;
        float4 v = make_float4(0.f, 0.f, 0.f, 0.f);
        if (base + row < N_NODES) v = ((const float4*)u)[(base + row) * 12 + kq];
        *(float4*)&sU[row * PADD + kq * 4] = v;
    }
    __syncthreads();

    const int cg = t & 7, rg = t >> 3;
    const int r0 = rg * 2, c0 = cg * 6;

    {
        float g[2][6];
        #pragma unroll
        for (int r = 0; r < 2; r++)
            #pragma unroll
            for (int c = 0; c < 6; c++) g[r][c] = 0.f;

        #pragma unroll 2
        for (int kq = 0; kq < 12; kq++) {
            float4 x0 = *(const float4*)&sU[(r0 + 0) * PADD + kq * 4];
            float4 x1 = *(const float4*)&sU[(r0 + 1) * PADD + kq * 4];
            #pragma unroll
            for (int c = 0; c < 6; c++) {
                float4 w = *(const float4*)&sW2[(c0 + c) * PADD + kq * 4];
                g[0][c] += x0.x * w.x + x0.y * w.y + x0.z * w.z + x0.w * w.w;
                g[1][c] += x1.x * w.x + x1.y * w.y + x1.z * w.z + x1.w * w.w;
            }
        }
        #pragma unroll
        for (int c = 0; c < 6; c++) {
            float bb = b2[c0 + c];
            float sc = bng[c0 + c] * rsqrtf(bnv[c0 + c] + BN_EPS);
            float sh = bnb[c0 + c] - bnm[c0 + c] * sc;
            #pragma unroll
            for (int r = 0; r < 2; r++) {
                float rl = fmaxf(g[r][c] + bb, 0.f);
                sG[(r0 + r) * PADD + c0 + c] = rl * sc + sh;
            }
        }
    }
    __syncthreads();

    {
        float a3[2][6], a4[2][6];
        #pragma unroll
        for (int r = 0; r < 2; r++)
            #pragma unroll
            for (int c = 0; c < 6; c++) { a3[r][c] = 0.f; a4[r][c] = 0.f; }

        #pragma unroll 2
        for (int kq = 0; kq < 12; kq++) {
            float4 x0 = *(const float4*)&sG[(r0 + 0) * PADD + kq * 4];
            float4 x1 = *(const float4*)&sG[(r0 + 1) * PADD + kq * 4];
            float4 p0 = make_float4(fmaxf(x0.x, 0.f), fmaxf(x0.y, 0.f), fmaxf(x0.z, 0.f), fmaxf(x0.w, 0.f));
            float4 p1 = make_float4(fmaxf(x1.x, 0.f), fmaxf(x1.y, 0.f), fmaxf(x1.z, 0.f), fmaxf(x1.w, 0.f));
            #pragma unroll
            for (int c = 0; c < 6; c++) {
                float4 w = *(const float4*)&sW1[(c0 + c) * PADD + kq * 4];
                a3[0][c] += x0.x * w.x + x0.y * w.y + x0.z * w.z + x0.w * w.w;
                a3[1][c] += x1.x * w.x + x1.y * w.y + x1.z * w.z + x1.w * w.w;
                a4[0][c] += p0.x * w.x + p0.y * w.y + p0.z * w.z + p0.w * w.w;
                a4[1][c] += p1.x * w.x + p1.y * w.y + p1.z * w.z + p1.w * w.w;
            }
        }
        #pragma unroll
        for (int r = 0; r < 2; r++) {
            int gr = base + r0 + r;
            if (gr < N_NODES) {
                #pragma unroll
                for (int c = 0; c < 3; c++) {
                    *(float2*)&t3[gr * DIM + c0 + 2 * c] = make_float2(a3[r][2 * c], a3[r][2 * c + 1]);
                    *(__half2*)&t4[gr * DIM + c0 + 2 * c] =
                        __float22half2_rn(make_float2(a4[r][2 * c], a4[r][2 * c + 1]));
                }
            }
        }
    }
}

// ---------------- chain2: v2=u2@c2W2+b2; g2=bn2(relu); z=relu(g2@fc1+b); out=z@fc2+b ----------------

__global__ __launch_bounds__(256) void k_chain2(const float* __restrict__ u2,
                                                const float* __restrict__ W2,
                                                const float* __restrict__ b2,
                                                const float* __restrict__ bng,
                                                const float* __restrict__ bnb,
                                                const float* __restrict__ bnm,
                                                const float* __restrict__ bnv,
                                                const float* __restrict__ fc1W,
                                                const float* __restrict__ fc1b,
                                                const float* __restrict__ fc2W,
                                                const float* __restrict__ fc2b,
                                                float* __restrict__ out) {
    __shared__ float sA[64 * PADD];
    __shared__ float sB[64 * PADD];
    __shared__ float sWa[DIM * PADD];
    __shared__ float sWb[DIM * PADD];
    __shared__ float sWc[N_CLASS * PADD];
    const int t = threadIdx.x;
    const int base = blockIdx.x * 64;

    for (int idx = t; idx < DIM * DIM; idx += 256) {
        int k = idx / DIM, c = idx - k * DIM;
        sWa[c * PADD + k] = W2[idx];
        sWb[c * PADD + k] = fc1W[idx];
    }
    for (int idx = t; idx < DIM * N_CLASS; idx += 256) {
        int k = idx / N_CLASS, c = idx - k * N_CLASS;
        sWc[c * PADD + k] = fc2W[idx];
    }
    for (int idx = t; idx < 64 * 12; idx += 256) {
        int row = idx / 12, kq = idx - row * 12;
        float4 v = make_float4(0.f, 0.f, 0.f, 0.f);
        if (base + row < N_NODES) v = ((const float4*)u2)[(base + row) * 12 + kq];
        *(float4*)&sA[row * PADD + kq * 4] = v;
    }
    __syncthreads();

    const int cg = t & 7, rg = t >> 3;
    const int r0 = rg * 2, c0 = cg * 6;

    {
        float g[2][6];
        #pragma unroll
        for (int r = 0; r < 2; r++)
            #pragma unroll
            for (int c = 0; c < 6; c++) g[r][c] = 0.f;
        #pragma unroll 2
        for (int kq = 0; kq < 12; kq++) {
            float4 x0 = *(const float4*)&sA[(r0 + 0) * PADD + kq * 4];
            float4 x1 = *(const float4*)&sA[(r0 + 1) * PADD + kq * 4];
            #pragma unroll
            for (int c = 0; c < 6; c++) {
                float4 w = *(const float4*)&sWa[(c0 + c) * PADD + kq * 4];
                g[0][c] += x0.x * w.x + x0.y * w.y + x0.z * w.z + x0.w * w.w;
                g[1][c] += x1.x * w.x + x1.y * w.y + x1.z * w.z + x1.w * w.w;
            }
        }
        #pragma unroll
        for (int c = 0; c < 6; c++) {
            float bb = b2[c0 + c];
            float sc = bng[c0 + c] * rsqrtf(bnv[c0 + c] + BN_EPS);
            float sh = bnb[c0 + c] - bnm[c0 + c] * sc;
            #pragma unroll
            for (int r = 0; r < 2; r++) {
                float rl = fmaxf(g[r][c] + bb, 0.f);
                sB[(r0 + r) * PADD + c0 + c] = rl * sc + sh;
            }
        }
    }
    __syncthreads();

    {
        float z[2][6];
        #pragma unroll
        for (int r = 0; r < 2; r++)
            #pragma unroll
            for (int c = 0; c < 6; c++) z[r][c] = 0.f;
        #pragma unroll 2
        for (int kq = 0; kq < 12; kq++) {
            float4 x0 = *(const float4*)&sB[(r0 + 0) * PADD + kq * 4];
            float4 x1 = *(const float4*)&sB[(r0 + 1) * PADD + kq * 4];
            #pragma unroll
            for (int c = 0; c < 6; c++) {
                float4 w = *(const float4*)&sWb[(c0 + c) * PADD + kq * 4];
                z[0][c] += x0.x * w.x + x0.y * w.y + x0.z * w.z + x0.w * w.w;
                z[1][c] += x1.x * w.x + x1.y * w.y + x1.z * w.z + x1.w * w.w;
            }
        }
        __syncthreads();
        #pragma unroll
        for (int c = 0; c < 6; c++) {
            float bb = fc1b[c0 + c];
            #pragma unroll
            for (int r = 0; r < 2; r++)
                sA[(r0 + r) * PADD + c0 + c] = fmaxf(z[r][c] + bb, 0.f);
        }
    }
    __syncthreads();

    if (cg < 6) {
        const int cc0 = cg * 3;
        float o[2][3];
        #pragma unroll
        for (int r = 0; r < 2; r++)
            #pragma unroll
            for (int c = 0; c < 3; c++) o[r][c] = 0.f;
        #pragma unroll 2
        for (int kq = 0; kq < 12; kq++) {
            float4 x0 = *(const float4*)&sA[(r0 + 0) * PADD + kq * 4];
            float4 x1 = *(const float4*)&sA[(r0 + 1) * PADD + kq * 4];
            #pragma unroll
            for (int c = 0; c < 3; c++) {
                float4 w = *(const float4*)&sWc[(cc0 + c) * PADD + kq * 4];
                o[0][c] += x0.x * w.x + x0.y * w.y + x0.z * w.z + x0.w * w.w;
                o[1][c] += x1.x * w.x + x1.y * w.y + x1.z * w.z + x1.w * w.w;
            }
        }
        #pragma unroll
        for (int r = 0; r < 2; r++) {
            int gr = base + r0 + r;
            if (gr < N_NODES) {
                #pragma unroll
                for (int c = 0; c < 3; c++)
                    out[gr * N_CLASS + cc0 + c] = o[r][c] + fc2b[cc0 + c];
            }
        }
    }
}

// ---------------- launch ----------------

extern "C" void kernel_launch(void* const* d_in, const int* in_sizes, int n_in,
                              void* d_out, int out_size, void* d_ws, size_t ws_size,
                              hipStream_t stream) {
    const float* x     = (const float*)d_in[0];
    const int*   ei    = (const int*)d_in[1];
    const float* c1_W1 = (const float*)d_in[2];
    const float* c1_b1 = (const float*)d_in[3];
    const float* c1_W2 = (const float*)d_in[4];
    const float* c1_b2 = (const float*)d_in[5];
    const float* c2_W1 = (const float*)d_in[6];
    const float* c2_b1 = (const float*)d_in[7];
    const float* c2_W2 = (const float*)d_in[8];
    const float* c2_b2 = (const float*)d_in[9];
    const float* bn1_g = (const float*)d_in[10];
    const float* bn1_b = (const float*)d_in[11];
    const float* bn1_m = (const float*)d_in[12];
    const float* bn1_v = (const float*)d_in[13];
    const float* bn2_g = (const float*)d_in[14];
    const float* bn2_b = (const float*)d_in[15];
    const float* bn2_m = (const float*)d_in[16];
    const float* bn2_v = (const float*)d_in[17];
    const float* fc1_W = (const float*)d_in[18];
    const float* fc1_b = (const float*)d_in[19];
    const float* fc2_W = (const float*)d_in[20];
    const float* fc2_b = (const float*)d_in[21];
    float* out = (float*)d_out;

    char* ws = (char*)d_ws;
    size_t o = 0;
    auto take = [&](size_t bytes) {
        void* p = ws + o;
        o = (o + bytes + 255) & ~(size_t)255;
        return p;
    };
    unsigned int* pairs = (unsigned int*)take((size_t)N_EDGES * 4);   // 12.8 MB (packed)
    int*  sorted_src    = (int*)take((size_t)N_EDGES * 4);            // 12.8 MB
    int*  row_ptr       = (int*)take((size_t)(N_NODES + 1) * 4);
    int*  bcnt          = (int*)take((size_t)NBUCK * 4);
    int*  bptr          = (int*)take((size_t)(NBUCK + 1) * 4);
    int*  bcursor       = (int*)take((size_t)NBUCK * 4);
    float*  t1          = (float*)take((size_t)N_NODES * DIM * 4);    // aliased: t1/u/t3/u2 (fp32)
    __half* t2h         = (__half*)take((size_t)N_NODES * DIM * 2);   // t2/t4 (fp16 messages)
    (void)ws_size; (void)in_sizes; (void)n_in; (void)out_size;

    const int NB64 = (N_NODES + 63) / 64;   // 1563
    const int NB20 = (N_NODES + 19) / 20;   // 5000

    hipMemsetAsync(bcnt, 0, (size_t)NBUCK * 4, stream);
    k_bhist<<<NBLK_E, 256, 0, stream>>>(ei, bcnt);
    k_bscan<<<1, 1024, 0, stream>>>(bcnt, bptr, bcursor);
    k_bin<<<NBLK_E, 256, 0, stream>>>(ei, bcursor, pairs);
    k_sort<<<NBUCK, 256, 0, stream>>>(pairs, bptr, row_ptr, sorted_src);

    k_g1<<<NB64, 256, 0, stream>>>(x, c1_W1, t1, t2h);
    k_aggr<<<NB20, 256, 0, stream>>>(t1, (const uint2*)t2h, row_ptr, sorted_src, c1_b1, t1);
    k_chain1<<<NB64, 256, 0, stream>>>(t1, c1_W2, c1_b2, bn1_g, bn1_b, bn1_m, bn1_v,
                                       c2_W1, t1, t2h);
    k_aggr<<<NB20, 256, 0, stream>>>(t1, (const uint2*)t2h, row_ptr, sorted_src, c2_b1, t1);
    k_chain2<<<NB64, 256, 0, stream>>>(t1, c2_W2, c2_b2, bn2_g, bn2_b, bn2_m, bn2_v,
                                       fc1_W, fc1_b, fc2_W, fc2_b, out);
}